// Round 13
// baseline (322.870 us; speedup 1.0000x reference)
//
#include <hip/hip_runtime.h>
#include <math.h>

// (B,L,H,P) = (4,4096,512,512)
#define Bz 4
#define Lz 4096
#define Hz 512
#define Pz 512
#define Nz (Bz*Lz)          // 16384 rows
#define CL 64               // scan chunk length
#define NC (Lz/CL)          // 64 chunks
#define CS (Bz*NC*Pz)       // 131072 carry slots
#define EPSf 1e-5f

typedef unsigned short u16;
typedef unsigned int   u32;
typedef __attribute__((ext_vector_type(8))) short bf16x8;
typedef __attribute__((ext_vector_type(8))) short short8v;
typedef __attribute__((ext_vector_type(4))) float f32x4;

__device__ __forceinline__ float gelu_exact(float x){
    return 0.5f * x * (1.0f + erff(x * 0.70710678118654752f));
}
__device__ __forceinline__ u16 f2b(float f){
    union { float f; u32 u; } v; v.f = f;
    u32 u = v.u;
    u32 r = (u + 0x7FFFu + ((u >> 16) & 1u)) >> 16;   // RTNE
    return (u16)r;
}
__device__ __forceinline__ float b2f(u16 h){
    union { u32 u; float f; } v; v.u = ((u32)h) << 16; return v.f;
}

// vectorized 8-element row loads (G13)
__device__ __forceinline__ void load8(const float* p, float* v){
    f32x4 a = *(const f32x4*)p, c = *(const f32x4*)(p+4);
    #pragma unroll
    for (int j=0;j<4;++j){ v[j]=a[j]; v[4+j]=c[j]; }
}
__device__ __forceinline__ void load8(const u16* p, float* v){
    short8v s = *(const short8v*)p;
    #pragma unroll
    for (int j=0;j<8;++j) v[j] = b2f((u16)s[j]);
}

// ---------------- setup: per-state SSM params ----------------
__global__ void setup_kernel(const float* __restrict__ Lre, const float* __restrict__ Lim,
                             const float* __restrict__ log_step,
                             float* __restrict__ prm){
    int p = blockIdx.x*blockDim.x + threadIdx.x;
    if (p >= Pz) return;
    float lr = Lre[p], li = Lim[p];
    float dt = expf(log_step[p]);
    float ar = lr*dt, ai = li*dt;
    float e = expf(ar);
    float Abr = e*cosf(ai), Abi = e*sinf(ai);   // Lambda_bar
    prm[p]        = Abr;
    prm[Pz + p]   = Abi;
    float nr = Abr - 1.0f, ni = Abi;
    float d2 = lr*lr + li*li;
    prm[2*Pz + p] = (nr*lr + ni*li)/d2;   // fRe
    prm[3*Pz + p] = (ni*lr - nr*li)/d2;   // fIm
    float arC = ar*(float)CL, aiC = ai*(float)CL;
    float eC = expf(arC);
    prm[4*Pz + p] = eC*cosf(aiC);         // ApowRe
    prm[5*Pz + p] = eC*sinf(aiC);         // ApowIm
}

// ---------------- merged weight converts (one launch) ----------------
// Interleaved complex layout: g col 2p = Re_p, 2p+1 = Im_p.
// Bcat row 2p = B_re row p, row 2p+1 = B_im row p  ([1024,512])
// Ccat col 2p = C_re col p, col 2p+1 = -C_im col p ([512,1024])
__global__ __launch_bounds__(256) void cvt_all(const float* __restrict__ B_re,
                                               const float* __restrict__ B_im,
                                               const float* __restrict__ C_re,
                                               const float* __restrict__ C_im,
                                               const float* __restrict__ W_enc,
                                               const float* __restrict__ W_dec,
                                               u16* __restrict__ Bcat,
                                               u16* __restrict__ Ccat,
                                               u16* __restrict__ Wenc,
                                               u16* __restrict__ Wdec){
    const int Q = 512*512;
    int i = blockIdx.x*256 + threadIdx.x;
    if (i < Q){ int p=i>>9, h=i&511; Bcat[(size_t)(2*p)*512 + h]   = f2b(B_re[i]); return; }
    i -= Q;
    if (i < Q){ int p=i>>9, h=i&511; Bcat[(size_t)(2*p+1)*512 + h] = f2b(B_im[i]); return; }
    i -= Q;
    if (i < Q){
        int h = i >> 9, p = i & 511;
        Ccat[(size_t)h*1024 + 2*p]     = f2b(C_re[i]);
        Ccat[(size_t)h*1024 + 2*p + 1] = f2b(-C_im[i]);
        return;
    }
    i -= Q;
    if (i < 2*Q){ Wenc[i] = f2b(W_enc[i]); return; }
    i -= 2*Q;
    Wdec[i] = f2b(W_dec[i]);
}

// ---------------- LayerNorm: wave-per-row, vectorized ----------------
template<typename T>
__global__ __launch_bounds__(256) void ln_kernel(const T* __restrict__ in,
                                                 const float* __restrict__ w,
                                                 const float* __restrict__ b,
                                                 u16* __restrict__ ob){
    int row = blockIdx.x*4 + (threadIdx.x >> 6);
    int l = threadIdx.x & 63;
    float v[8];
    load8(in + (size_t)row*Hz + l*8, v);
    float s = 0.f, q = 0.f;
    #pragma unroll
    for (int j=0;j<8;++j){ s += v[j]; q += v[j]*v[j]; }
    #pragma unroll
    for (int o=32;o;o>>=1){ s += __shfl_xor(s,o); q += __shfl_xor(q,o); }
    float mu = s * (1.0f/512.0f);
    float rs = rsqrtf(q * (1.0f/512.0f) - mu*mu + EPSf);
    short8v o8;
    #pragma unroll
    for (int j=0;j<8;++j){
        int m = l*8 + j;
        o8[j] = (short)f2b((v[j]-mu)*rs*w[m] + b[m]);
    }
    *(short8v*)&ob[(size_t)row*Hz + l*8] = o8;
}

// ============ Register GEMM family: no LDS staging, no barriers ============
// C[N,M] = A[N,K] @ Bw[M,K]^T. Block 256 thr = 4 waves (2n x 2m), wave 64x64.
// Each lane loads its MFMA frags straight from global (16 rows x 64B lines,
// fully coalesced at line granularity; B + re-read A panels are L2-resident).
// No __syncthreads / vmcnt(0) in the loop — the drain that pinned all 7
// LDS-staged variants at ~3000 cy*CU/step is gone; 4 waves/SIMD hide L2 lat.
#define EB16 0
#define EY   1
#define ERES 2

template<int K, int EPI>
__global__ __launch_bounds__(256, 4)
void gemmr(const u16* __restrict__ A, const u16* __restrict__ Bw, int M,
           u16* __restrict__ outB,
           const u16* __restrict__ fxB,        // EY: bf16 residual fx
           const float* __restrict__ Dv,       // EY
           const u16* __restrict__ resB,       // ERES
           float* __restrict__ outF)           // ERES
{
    int nx = gridDim.x, ny = gridDim.y;
    int nwg = nx*ny;
    int lid = blockIdx.x + blockIdx.y*nx;
    int cpx = nwg >> 3;
    int gdx = (lid & 7)*cpx + (lid >> 3);
    int n0 = (gdx / ny) * 128;
    int m0 = (gdx % ny) * 128;

    int l = threadIdx.x & 63;
    int w = threadIdx.x >> 6;
    int wr = w >> 1, wc = w & 1;
    int rbase = wr*64, cbase = wc*64;
    int lr15 = l & 15;
    int koff = (l >> 4) * 8;

    const u16* Ap = A  + (size_t)(n0 + rbase + lr15)*K + koff;
    const u16* Bp = Bw + (size_t)(m0 + cbase + lr15)*K + koff;

    f32x4 acc[4][4];
    #pragma unroll
    for (int i=0;i<4;++i)
        #pragma unroll
        for (int j=0;j<4;++j) acc[i][j] = (f32x4)(0.f);

    for (int k0 = 0; k0 < K; k0 += 32){
        bf16x8 af[4], bf[4];
        #pragma unroll
        for (int i=0;i<4;++i) af[i] = *(const bf16x8*)(Ap + (size_t)(16*i)*K + k0);
        #pragma unroll
        for (int j=0;j<4;++j) bf[j] = *(const bf16x8*)(Bp + (size_t)(16*j)*K + k0);
        #pragma unroll
        for (int i=0;i<4;++i)
            #pragma unroll
            for (int j=0;j<4;++j)
                acc[i][j] = __builtin_amdgcn_mfma_f32_16x16x32_bf16(af[i], bf[j], acc[i][j], 0,0,0);
    }

    int er = (l >> 4) * 4;
    int ec = l & 15;
    #pragma unroll
    for (int fm=0; fm<4; ++fm)
        #pragma unroll
        for (int fn=0; fn<4; ++fn)
            #pragma unroll
            for (int q=0; q<4; ++q){
                int n = n0 + rbase + fm*16 + er + q;
                int m = m0 + cbase + fn*16 + ec;
                float v = acc[fm][fn][q];
                if (EPI == EB16){
                    outB[(size_t)n*M + m] = f2b(v);
                } else if (EPI == EY){
                    size_t idx = (size_t)n*Hz + m;
                    float fxv = b2f(fxB[idx]);
                    float y = 2.0f*v + Dv[m]*fxv;
                    outB[idx] = f2b(gelu_exact(y) + fxv);
                } else {
                    size_t idx = (size_t)n*Hz + m;
                    outF[idx] = v + b2f(resB[idx]);
                }
            }
}

// ---- register GEMM1 + fused scan-phase1 (interleaved g layout) ----
// Block 128 rows (2 chunks) x 128 cols (64 complex states). Epilogue stores
// the tile to a 32KB LDS buffer, then 128 threads scan 64 rows each -> E.
__global__ __launch_bounds__(256, 4)
void gemm1r_scan(const u16* __restrict__ A, const u16* __restrict__ Bw,
                 u16* __restrict__ outB,
                 const float* __restrict__ prm,
                 float* __restrict__ ERe, float* __restrict__ EIm)
{
    constexpr int K = 512;
    __shared__ u16 gt[128*128];    // epilogue-only, 32KB

    int nx = gridDim.x, ny = gridDim.y;
    int nwg = nx*ny;
    int lid = blockIdx.x + blockIdx.y*nx;
    int cpx = nwg >> 3;
    int gdx = (lid & 7)*cpx + (lid >> 3);
    int n0 = (gdx / ny) * 128;
    int m0 = (gdx % ny) * 128;

    int l = threadIdx.x & 63;
    int w = threadIdx.x >> 6;
    int wr = w >> 1, wc = w & 1;
    int rbase = wr*64, cbase = wc*64;
    int lr15 = l & 15;
    int koff = (l >> 4) * 8;

    const u16* Ap = A  + (size_t)(n0 + rbase + lr15)*K + koff;
    const u16* Bp = Bw + (size_t)(m0 + cbase + lr15)*K + koff;

    f32x4 acc[4][4];
    #pragma unroll
    for (int i=0;i<4;++i)
        #pragma unroll
        for (int j=0;j<4;++j) acc[i][j] = (f32x4)(0.f);

    for (int k0 = 0; k0 < K; k0 += 32){
        bf16x8 af[4], bf[4];
        #pragma unroll
        for (int i=0;i<4;++i) af[i] = *(const bf16x8*)(Ap + (size_t)(16*i)*K + k0);
        #pragma unroll
        for (int j=0;j<4;++j) bf[j] = *(const bf16x8*)(Bp + (size_t)(16*j)*K + k0);
        #pragma unroll
        for (int i=0;i<4;++i)
            #pragma unroll
            for (int j=0;j<4;++j)
                acc[i][j] = __builtin_amdgcn_mfma_f32_16x16x32_bf16(af[i], bf[j], acc[i][j], 0,0,0);
    }

    int er = (l >> 4) * 4;
    int ec = l & 15;
    #pragma unroll
    for (int fm=0; fm<4; ++fm)
        #pragma unroll
        for (int fn=0; fn<4; ++fn)
            #pragma unroll
            for (int q=0; q<4; ++q){
                int rr = rbase + fm*16 + er + q;
                int cc = cbase + fn*16 + ec;
                u16 hv = f2b(acc[fm][fn][q]);
                outB[(size_t)(n0 + rr)*1024 + (m0 + cc)] = hv;
                gt[rr*128 + cc] = hv;
            }
    __syncthreads();

    int tid = threadIdx.x;
    if (tid < 128){
        int p = tid & 63, h = tid >> 6;
        int P = (m0 >> 1) + p;
        int b = n0 >> 12;
        int c = ((n0 & 4095) >> 6) + h;
        float Ar = prm[P], Ai = prm[Pz+P];
        float fre = prm[2*Pz+P], fim = prm[3*Pz+P];
        float xr = 0.f, xi = 0.f;
        int base = h*64*128 + 2*p;
        #pragma unroll 8
        for (int r = 0; r < 64; ++r){
            u32 v = *(const u32*)&gt[base + r*128];
            float gr = b2f((u16)(v & 0xffff));
            float gi = b2f((u16)(v >> 16));
            float br = fre*gr - fim*gi;
            float bi = fre*gi + fim*gr;
            float nr2 = Ar*xr - Ai*xi + br;
            float ni2 = Ar*xi + Ai*xr + bi;
            xr = nr2; xi = ni2;
        }
        size_t ci = ((size_t)(b*NC + c))*Pz + P;
        ERe[ci] = xr; EIm[ci] = xi;
    }
}

// ---- register GEMM3 + fused GEGLU ----
// Block 128 rows x 128 virtual cols (= 64 ff cols). Virtual col group
// gl = wc*4+fn: even -> a-row (Wenc[fb + (gl>>1)*16 + r]), odd -> g-row
// (Wenc[512 + fb + (gl>>1)*16 + r]). Epilogue: ff = a * gelu(g) in-register.
__global__ __launch_bounds__(256, 4)
void gemm3r_glu(const u16* __restrict__ A, const u16* __restrict__ Wenc,
                u16* __restrict__ outB)
{
    constexpr int K = 512;
    int nx = gridDim.x, ny = gridDim.y;
    int nwg = nx*ny;
    int lid = blockIdx.x + blockIdx.y*nx;
    int cpx = nwg >> 3;
    int gdx = (lid & 7)*cpx + (lid >> 3);
    int n0 = (gdx / ny) * 128;
    int fb = (gdx % ny) * 64;      // ff-col block base

    int l = threadIdx.x & 63;
    int w = threadIdx.x >> 6;
    int wr = w >> 1, wc = w & 1;
    int rbase = wr*64;
    int lr15 = l & 15;
    int koff = (l >> 4) * 8;

    const u16* Ap = A + (size_t)(n0 + rbase + lr15)*K + koff;
    const u16* Bp[4];
    #pragma unroll
    for (int fn=0; fn<4; ++fn){
        int gl = wc*4 + fn;
        int row = ((gl & 1) ? 512 : 0) + fb + (gl >> 1)*16 + lr15;
        Bp[fn] = Wenc + (size_t)row*K + koff;
    }

    f32x4 acc[4][4];
    #pragma unroll
    for (int i=0;i<4;++i)
        #pragma unroll
        for (int j=0;j<4;++j) acc[i][j] = (f32x4)(0.f);

    for (int k0 = 0; k0 < K; k0 += 32){
        bf16x8 af[4], bf[4];
        #pragma unroll
        for (int i=0;i<4;++i) af[i] = *(const bf16x8*)(Ap + (size_t)(16*i)*K + k0);
        #pragma unroll
        for (int j=0;j<4;++j) bf[j] = *(const bf16x8*)(Bp[j] + k0);
        #pragma unroll
        for (int i=0;i<4;++i)
            #pragma unroll
            for (int j=0;j<4;++j)
                acc[i][j] = __builtin_amdgcn_mfma_f32_16x16x32_bf16(af[i], bf[j], acc[i][j], 0,0,0);
    }

    int er = (l >> 4) * 4;
    int ec = l & 15;
    #pragma unroll
    for (int fm=0; fm<4; ++fm)
        #pragma unroll
        for (int pr=0; pr<2; ++pr)
            #pragma unroll
            for (int q=0; q<4; ++q){
                int n = n0 + rbase + fm*16 + er + q;
                int col = fb + (wc*2 + pr)*16 + ec;
                float ffv = acc[fm][2*pr][q] * gelu_exact(acc[fm][2*pr+1][q]);
                outB[(size_t)n*Hz + col] = f2b(ffv);
            }
}

// ---------------- scan combine (unchanged) ----------------
__global__ __launch_bounds__(256) void scan_combine(const float* __restrict__ ERe,
                                                    const float* __restrict__ EIm,
                                                    const float* __restrict__ prm,
                                                    float* __restrict__ SinRe,
                                                    float* __restrict__ SinIm){
    int gt = blockIdx.x*256 + threadIdx.x;   // over B*P
    int b = gt / Pz, p = gt % Pz;
    float Ar = prm[4*Pz+p], Ai = prm[5*Pz+p];
    float Sr = 0.f, Si = 0.f;
    for (int c = 0; c < NC; ++c) {
        size_t idx = ((size_t)(b*NC + c))*Pz + p;
        SinRe[idx] = Sr; SinIm[idx] = Si;
        float er = ERe[idx], ei = EIm[idx];
        float nr = Ar*Sr - Ai*Si + er;
        float ni = Ar*Si + Ai*Sr + ei;
        Sr = nr; Si = ni;
    }
}

// ---------------- scan phase2: interleaved, short8 (16B) per row ------------
__global__ __launch_bounds__(64) void scan_phase2(u16* __restrict__ g,
                                                  const float* __restrict__ prm,
                                                  const float* __restrict__ SinRe,
                                                  const float* __restrict__ SinIm){
    int t = blockIdx.x;
    int ph = t & 1; t >>= 1;
    int c  = t % NC;
    int b  = t / NC;
    int p0 = ph*256 + threadIdx.x*4;         // first of 4 states
    int cb = 2*p0;
    size_t base = ((size_t)(b*Lz + c*CL))*1024;
    size_t ci = ((size_t)(b*NC + c))*Pz + p0;
    float Ar[4], Ai[4], fr[4], fi[4], xr[4], xi[4];
    f32x4 sr4 = *(const f32x4*)&SinRe[ci];
    f32x4 si4 = *(const f32x4*)&SinIm[ci];
    #pragma unroll
    for (int j=0;j<4;++j){
        Ar[j]=prm[p0+j]; Ai[j]=prm[Pz+p0+j];
        fr[j]=prm[2*Pz+p0+j]; fi[j]=prm[3*Pz+p0+j];
        xr[j]=sr4[j]; xi[j]=si4[j];
    }
    for (int ll=0; ll<CL; ++ll){
        short8v v8 = *(const short8v*)&g[base + cb];
        short8v o8;
        #pragma unroll
        for (int j=0;j<4;++j){
            float gr = b2f((u16)v8[2*j]), gi = b2f((u16)v8[2*j+1]);
            float br = fr[j]*gr - fi[j]*gi;
            float bi = fr[j]*gi + fi[j]*gr;
            float nr = Ar[j]*xr[j] - Ai[j]*xi[j] + br;
            float ni = Ar[j]*xi[j] + Ai[j]*xr[j] + bi;
            xr[j]=nr; xi[j]=ni;
            o8[2*j]   = (short)f2b(nr);
            o8[2*j+1] = (short)f2b(ni);
        }
        *(short8v*)&g[base + cb] = o8;
        base += 1024;
    }
}

extern "C" void kernel_launch(void* const* d_in, const int* in_sizes, int n_in,
                              void* d_out, int out_size, void* d_ws, size_t ws_size,
                              hipStream_t stream) {
    const float* x        = (const float*)d_in[0];
    const float* ln1_w    = (const float*)d_in[1];
    const float* ln1_b    = (const float*)d_in[2];
    const float* Lre      = (const float*)d_in[3];
    const float* Lim      = (const float*)d_in[4];
    const float* B_re     = (const float*)d_in[5];
    const float* B_im     = (const float*)d_in[6];
    const float* C_re     = (const float*)d_in[7];
    const float* C_im     = (const float*)d_in[8];
    const float* Dv       = (const float*)d_in[9];
    const float* log_step = (const float*)d_in[10];
    const float* ln2_w    = (const float*)d_in[11];
    const float* ln2_b    = (const float*)d_in[12];
    const float* W_enc    = (const float*)d_in[13];
    const float* W_dec    = (const float*)d_in[14];
    float* out = (float*)d_out;

    const size_t NH = (size_t)Nz*Hz;   // 8388608
    char* W = (char*)d_ws;
    u16*   fxb  = (u16*)  (W);                    // [N,512] bf16: fx, later ff
    u16*   g    = (u16*)  (W + NH*2);             // [N,1024] bf16 interleaved: g -> xs
    u16*   hb   = (u16*)  (W + NH*6);             // [N,512] bf16: h
    u16*   fx2b = (u16*)  (W + NH*8);             // [N,512] bf16: fx2
    float* ERe  = (float*)(W + NH*10);
    float* EIm  = ERe + CS;
    float* SinRe= EIm + CS;
    float* SinIm= SinRe + CS;
    float* prm  = SinIm + CS;                     // 6*Pz f32
    u16*   Bcat = (u16*)(prm + 6*Pz);             // [1024,512] interleaved rows
    u16*   Ccat = Bcat + 1024*512;                // [512,1024] interleaved cols
    u16*   Wenc = Ccat + 512*1024;                // [1024,512]
    u16*   Wdec = Wenc + 1024*512;                // [512,512]

    setup_kernel<<<dim3(2), dim3(256), 0, stream>>>(Lre, Lim, log_step, prm);

    cvt_all<<<dim3(6*1024), dim3(256), 0, stream>>>(B_re, B_im, C_re, C_im, W_enc, W_dec,
                                                    Bcat, Ccat, Wenc, Wdec);

    // LN1: x -> fxb (bf16)
    ln_kernel<float><<<dim3(Nz/4), dim3(256), 0, stream>>>(x, ln1_w, ln1_b, fxb);

    // GEMM1 + scan-phase1 fused (register GEMM): grid 128x8 = 1024 blocks
    gemm1r_scan<<<dim3(Nz/128, 1024/128), dim3(256), 0, stream>>>(
        fxb, Bcat, g, prm, ERe, EIm);

    // scan combine + phase2 (in place over g)
    scan_combine<<<dim3((Bz*Pz)/256), dim3(256), 0, stream>>>(ERe, EIm, prm, SinRe, SinIm);
    scan_phase2<<<dim3(Bz*NC*2), dim3(64), 0, stream>>>(g, prm, SinRe, SinIm);

    // GEMM2 (Y): h = gelu(2*(xs@Ccat^T) + D*fx) + fx -> hb   grid 128x4
    gemmr<1024,EY><<<dim3(Nz/128, 512/128), dim3(256), 0, stream>>>(
        g, Ccat, 512, hb, fxb, Dv, nullptr, nullptr);

    // LN2: hb -> fx2b (bf16)
    ln_kernel<u16><<<dim3(Nz/4), dim3(256), 0, stream>>>(hb, ln2_w, ln2_b, fx2b);

    // GEMM3 + GEGLU fused (register GEMM): ff -> fxb   grid 128x8
    gemm3r_glu<<<dim3(Nz/128, 8), dim3(256), 0, stream>>>(fx2b, Wenc, fxb);

    // GEMM4: out = ff @ Wdec^T + fx2   grid 128x4
    gemmr<512,ERES><<<dim3(Nz/128, 512/128), dim3(256), 0, stream>>>(
        fxb, Wdec, 512, nullptr, nullptr, nullptr, fx2b, out);
}

// Round 14
// 174.426 us; speedup vs baseline: 1.8510x; 1.8510x over previous
//
#include <hip/hip_runtime.h>
#include <math.h>

// (B,L,H,P) = (4,4096,512,512)
#define Bz 4
#define Lz 4096
#define Hz 512
#define Pz 512
#define Nz (Bz*Lz)          // 16384 rows
#define CL 64               // scan chunk length
#define NC (Lz/CL)          // 64 chunks
#define CS (Bz*NC*Pz)       // 131072 carry slots
#define EPSf 1e-5f

typedef unsigned short u16;
typedef unsigned int   u32;
typedef __attribute__((ext_vector_type(8))) short bf16x8;
typedef __attribute__((ext_vector_type(8))) short short8v;
typedef __attribute__((ext_vector_type(4))) float f32x4;

__device__ __forceinline__ float gelu_exact(float x){
    return 0.5f * x * (1.0f + erff(x * 0.70710678118654752f));
}
__device__ __forceinline__ u16 f2b(float f){
    union { float f; u32 u; } v; v.f = f;
    u32 u = v.u;
    u32 r = (u + 0x7FFFu + ((u >> 16) & 1u)) >> 16;   // RTNE
    return (u16)r;
}
__device__ __forceinline__ float b2f(u16 h){
    union { u32 u; float f; } v; v.u = ((u32)h) << 16; return v.f;
}

__device__ __forceinline__ void gload_lds16(const u16* g, u16* l){
    __builtin_amdgcn_global_load_lds(
        (const __attribute__((address_space(1))) void*)g,
        (__attribute__((address_space(3))) void*)l, 16, 0, 0);
}

// vectorized 8-element row loads (G13)
__device__ __forceinline__ void load8(const float* p, float* v){
    f32x4 a = *(const f32x4*)p, c = *(const f32x4*)(p+4);
    #pragma unroll
    for (int j=0;j<4;++j){ v[j]=a[j]; v[4+j]=c[j]; }
}
__device__ __forceinline__ void load8(const u16* p, float* v){
    short8v s = *(const short8v*)p;
    #pragma unroll
    for (int j=0;j<8;++j) v[j] = b2f((u16)s[j]);
}

// ---------------- setup: per-state SSM params ----------------
__global__ void setup_kernel(const float* __restrict__ Lre, const float* __restrict__ Lim,
                             const float* __restrict__ log_step,
                             float* __restrict__ prm){
    int p = blockIdx.x*blockDim.x + threadIdx.x;
    if (p >= Pz) return;
    float lr = Lre[p], li = Lim[p];
    float dt = expf(log_step[p]);
    float ar = lr*dt, ai = li*dt;
    float e = expf(ar);
    float Abr = e*cosf(ai), Abi = e*sinf(ai);   // Lambda_bar
    prm[p]        = Abr;
    prm[Pz + p]   = Abi;
    float nr = Abr - 1.0f, ni = Abi;
    float d2 = lr*lr + li*li;
    prm[2*Pz + p] = (nr*lr + ni*li)/d2;   // fRe
    prm[3*Pz + p] = (ni*lr - nr*li)/d2;   // fIm
    float arC = ar*(float)CL, aiC = ai*(float)CL;
    float eC = expf(arC);
    prm[4*Pz + p] = eC*cosf(aiC);         // ApowRe
    prm[5*Pz + p] = eC*sinf(aiC);         // ApowIm
}

// ---------------- merged weight converts (one launch) ----------------
// Interleaved complex layout: g col 2p = Re_p, 2p+1 = Im_p.
// Bcat row 2p = B_re row p, row 2p+1 = B_im row p  ([1024,512])
// Ccat col 2p = C_re col p, col 2p+1 = -C_im col p ([512,1024])
__global__ __launch_bounds__(256) void cvt_all(const float* __restrict__ B_re,
                                               const float* __restrict__ B_im,
                                               const float* __restrict__ C_re,
                                               const float* __restrict__ C_im,
                                               const float* __restrict__ W_enc,
                                               const float* __restrict__ W_dec,
                                               u16* __restrict__ Bcat,
                                               u16* __restrict__ Ccat,
                                               u16* __restrict__ Wenc,
                                               u16* __restrict__ Wdec){
    const int Q = 512*512;
    int i = blockIdx.x*256 + threadIdx.x;
    if (i < Q){ int p=i>>9, h=i&511; Bcat[(size_t)(2*p)*512 + h]   = f2b(B_re[i]); return; }
    i -= Q;
    if (i < Q){ int p=i>>9, h=i&511; Bcat[(size_t)(2*p+1)*512 + h] = f2b(B_im[i]); return; }
    i -= Q;
    if (i < Q){
        int h = i >> 9, p = i & 511;
        Ccat[(size_t)h*1024 + 2*p]     = f2b(C_re[i]);
        Ccat[(size_t)h*1024 + 2*p + 1] = f2b(-C_im[i]);
        return;
    }
    i -= Q;
    if (i < 2*Q){ Wenc[i] = f2b(W_enc[i]); return; }
    i -= 2*Q;
    Wdec[i] = f2b(W_dec[i]);
}

// ---------------- LayerNorm: wave-per-row, vectorized ----------------
template<typename T>
__global__ __launch_bounds__(256) void ln_kernel(const T* __restrict__ in,
                                                 const float* __restrict__ w,
                                                 const float* __restrict__ b,
                                                 u16* __restrict__ ob){
    int row = blockIdx.x*4 + (threadIdx.x >> 6);
    int l = threadIdx.x & 63;
    float v[8];
    load8(in + (size_t)row*Hz + l*8, v);
    float s = 0.f, q = 0.f;
    #pragma unroll
    for (int j=0;j<8;++j){ s += v[j]; q += v[j]*v[j]; }
    #pragma unroll
    for (int o=32;o;o>>=1){ s += __shfl_xor(s,o); q += __shfl_xor(q,o); }
    float mu = s * (1.0f/512.0f);
    float rs = rsqrtf(q * (1.0f/512.0f) - mu*mu + EPSf);
    short8v o8;
    #pragma unroll
    for (int j=0;j<8;++j){
        int m = l*8 + j;
        o8[j] = (short)f2b((v[j]-mu)*rs*w[m] + b[m]);
    }
    *(short8v*)&ob[(size_t)row*Hz + l*8] = o8;
}

// ============ Counted-vmcnt triple-buffer 256x128 MFMA GEMM ============
// C[N,M] = A[N,K] @ Bw[M,K]^T. BM=256, BN=128, BK=64, 512 threads (8 waves,
// 4M x 2N; per-wave 64x64 -> acc[4][4], 32 MFMA + 16 ds_read_b128 per K-tile).
// LDS: 3 buffers x (A 32KB + B 16KB) = 144KB -> 1 block/CU, 2 waves/SIMD.
// Per K-tile: vmcnt(6) [tile T landed; T+1's 6 loads/thread in flight] ->
// s_barrier -> stage tile T+2 into buf[(T+2)%3] -> ds_read + 32 MFMA.
// vmcnt NEVER drains to 0 mid-loop (T4); a staged tile gets 2 full K-tiles
// (>1000 cy) of cover — the sizing R4/R9 lacked. WAR-safe: buf[(T+2)%3] ==
// buf[(T-1)%3], whose reads all drained before each wave passed barrier_T.
#define EY    1
#define ERES  2
#define EGLU  3
#define ESCAN 4

#define ATW (256*64)
#define BTW (128*64)
#define TBW (ATW+BTW)

// A-tile 256x64 (32KB): 4 gload_lds/thread. Verified 0-conflict swizzle pair.
__device__ __forceinline__ void stageA256v(const u16* __restrict__ src, int ld,
                                           int row0, int kt, u16* lds){
    int lane = threadIdx.x & 63, w = threadIdx.x >> 6;
    #pragma unroll
    for (int q=0;q<4;++q){
        int c = w + q*8;                               // 1KB chunk, 0..31 (8 rows)
        int r = c*8 + (lane >> 3);                     // row 0..255
        int colE = 8*((lane & 7) ^ ((lane >> 3) & 7));
        gload_lds16(src + (size_t)(row0 + r)*ld + kt + colE, lds + c*512);
    }
}
// B-tile 128x64 (16KB): 2 gload_lds/thread
__device__ __forceinline__ void stageB128v(const u16* __restrict__ src, int ld,
                                           int row0, int kt, u16* lds){
    int lane = threadIdx.x & 63, w = threadIdx.x >> 6;
    #pragma unroll
    for (int q=0;q<2;++q){
        int c = w + q*8;                               // 0..15
        int r = c*8 + (lane >> 3);                     // row 0..127
        int colE = 8*((lane & 7) ^ ((lane >> 3) & 7));
        gload_lds16(src + (size_t)(row0 + r)*ld + kt + colE, lds + c*512);
    }
}
// GEGLU virtual-B: 16-row frags alternate a-rows / g-rows of Wenc (K=512)
__device__ __forceinline__ void stageBglu(const u16* __restrict__ Wenc, int fb,
                                          int kt, u16* lds){
    int lane = threadIdx.x & 63, w = threadIdx.x >> 6;
    #pragma unroll
    for (int q=0;q<2;++q){
        int c = w + q*8;
        int v = c*8 + (lane >> 3);                     // virtual row 0..127
        int vf = v >> 4, r = v & 15;
        int grow = ((vf & 1) ? 512 : 0) + fb + (vf >> 1)*16 + r;
        int colE = 8*((lane & 7) ^ ((lane >> 3) & 7));
        gload_lds16(Wenc + (size_t)grow*512 + kt + colE, lds + c*512);
    }
}

template<int K, int EPI>
__global__ __launch_bounds__(512)
void gemmv(const u16* __restrict__ A, const u16* __restrict__ Bw, int M,
           u16* __restrict__ outB,
           const u16* __restrict__ fxB,        // EY
           const float* __restrict__ Dv,       // EY
           const u16* __restrict__ resB,       // ERES
           float* __restrict__ outF,           // ERES
           const float* __restrict__ prm,      // ESCAN
           float* __restrict__ ERe,            // ESCAN
           float* __restrict__ EIm)            // ESCAN
{
    constexpr int NT = K/64;
    __shared__ u16 LDS[3*TBW];   // 144KB

    int nx = gridDim.x, ny = gridDim.y;
    int nwg = nx*ny;
    int lid = blockIdx.x + blockIdx.y*nx;
    int cpx = nwg >> 3;
    int gdx = (lid & 7)*cpx + (lid >> 3);
    int n0 = (gdx / ny) * 256;
    int mb = gdx % ny;
    int m0 = mb * 128;          // output-col block (virtual for EGLU)
    int fb = mb * 64;           // EGLU ff-col base

    int l = threadIdx.x & 63;
    int w = threadIdx.x >> 6;
    int wm = w >> 1, wn = w & 1;
    int rb = wm*64, cb = wn*64;
    int lrow  = l & 15;
    int lcol0 = ((l >> 4)*8) ^ ((l & 7) << 3);
    int lcol1 = lcol0 ^ 32;

    f32x4 acc[4][4];
    #pragma unroll
    for (int i=0;i<4;++i)
        #pragma unroll
        for (int j=0;j<4;++j) acc[i][j] = (f32x4)(0.f);

    // prologue: stage tiles 0 and 1 (12 loads/thread outstanding)
    stageA256v(A, K, n0, 0, &LDS[0]);
    if (EPI==EGLU) stageBglu(Bw, fb, 0, &LDS[ATW]); else stageB128v(Bw, K, m0, 0, &LDS[ATW]);
    stageA256v(A, K, n0, 64, &LDS[TBW]);
    if (EPI==EGLU) stageBglu(Bw, fb, 64, &LDS[TBW+ATW]); else stageB128v(Bw, K, m0, 64, &LDS[TBW+ATW]);

    for (int T=0; T<NT; ++T){
        if (T == NT-1){ asm volatile("s_waitcnt vmcnt(0)" ::: "memory"); }
        else          { asm volatile("s_waitcnt vmcnt(6)" ::: "memory"); }
        __builtin_amdgcn_s_barrier();
        if (T+2 < NT){
            u16* buf = &LDS[((T+2)%3)*TBW];
            int ktn = (T+2)*64;
            stageA256v(A, K, n0, ktn, buf);
            if (EPI==EGLU) stageBglu(Bw, fb, ktn, buf+ATW); else stageB128v(Bw, K, m0, ktn, buf+ATW);
        }
        const u16* Ab = &LDS[(T%3)*TBW];
        const u16* Bb = Ab + ATW;
        bf16x8 a0[4], a1[4], b0[4], b1[4];
        #pragma unroll
        for (int f=0; f<4; ++f){
            a0[f] = *(const bf16x8*)&Ab[(rb + f*16 + lrow)*64 + lcol0];
            a1[f] = *(const bf16x8*)&Ab[(rb + f*16 + lrow)*64 + lcol1];
        }
        #pragma unroll
        for (int g=0; g<4; ++g){
            b0[g] = *(const bf16x8*)&Bb[(cb + g*16 + lrow)*64 + lcol0];
            b1[g] = *(const bf16x8*)&Bb[(cb + g*16 + lrow)*64 + lcol1];
        }
        __builtin_amdgcn_s_setprio(1);
        #pragma unroll
        for (int f=0; f<4; ++f)
            #pragma unroll
            for (int g=0; g<4; ++g){
                acc[f][g] = __builtin_amdgcn_mfma_f32_16x16x32_bf16(a0[f], b0[g], acc[f][g], 0,0,0);
                acc[f][g] = __builtin_amdgcn_mfma_f32_16x16x32_bf16(a1[f], b1[g], acc[f][g], 0,0,0);
            }
        __builtin_amdgcn_s_setprio(0);
    }

    // epilogue: C layout col=lane&15, row=(lane>>4)*4+q
    int er = (l >> 4) * 4;
    int ec = l & 15;

    if (EPI == ESCAN){
        u16* gt = (u16*)LDS;   // alias staging (dead); [256][128] u16 = 64KB
        __syncthreads();
        #pragma unroll
        for (int fm=0; fm<4; ++fm)
            #pragma unroll
            for (int g=0; g<4; ++g)
                #pragma unroll
                for (int q=0; q<4; ++q){
                    int rr = rb + fm*16 + er + q;
                    int cc = cb + g*16 + ec;
                    u16 hv = f2b(acc[fm][g][q]);
                    outB[(size_t)(n0 + rr)*M + (m0 + cc)] = hv;
                    gt[rr*128 + cc] = hv;
                }
        __syncthreads();
        int tid = threadIdx.x;
        if (tid < 256){
            int p = tid & 63, h = tid >> 6;          // state, chunk-in-block
            int P = (m0 >> 1) + p;
            int b = n0 >> 12;
            int c = ((n0 & 4095) >> 6) + h;
            float Ar = prm[P], Ai = prm[Pz+P];
            float fre = prm[2*Pz+P], fim = prm[3*Pz+P];
            float xr = 0.f, xi = 0.f;
            int base = h*64*128 + 2*p;
            #pragma unroll 8
            for (int r = 0; r < 64; ++r){
                u32 v = *(const u32*)&gt[base + r*128];
                float gr = b2f((u16)(v & 0xffff));
                float gi = b2f((u16)(v >> 16));
                float br = fre*gr - fim*gi;
                float bi = fre*gi + fim*gr;
                float nr2 = Ar*xr - Ai*xi + br;
                float ni2 = Ar*xi + Ai*xr + bi;
                xr = nr2; xi = ni2;
            }
            size_t ci = ((size_t)(b*NC + c))*Pz + P;
            ERe[ci] = xr; EIm[ci] = xi;
        }
    } else if (EPI == EGLU){
        #pragma unroll
        for (int fm=0; fm<4; ++fm)
            #pragma unroll
            for (int pr=0; pr<2; ++pr)
                #pragma unroll
                for (int q=0; q<4; ++q){
                    int n = n0 + rb + fm*16 + er + q;
                    int col = fb + (wn*2 + pr)*16 + ec;
                    float ffv = acc[fm][2*pr][q] * gelu_exact(acc[fm][2*pr+1][q]);
                    outB[(size_t)n*Hz + col] = f2b(ffv);
                }
    } else {
        #pragma unroll
        for (int fm=0; fm<4; ++fm)
            #pragma unroll
            for (int g=0; g<4; ++g)
                #pragma unroll
                for (int q=0; q<4; ++q){
                    int n = n0 + rb + fm*16 + er + q;
                    int m = m0 + cb + g*16 + ec;
                    float v = acc[fm][g][q];
                    if (EPI == EY){
                        size_t idx = (size_t)n*Hz + m;
                        float fxv = b2f(fxB[idx]);
                        float y = 2.0f*v + Dv[m]*fxv;
                        outB[idx] = f2b(gelu_exact(y) + fxv);
                    } else {  // ERES
                        size_t idx = (size_t)n*Hz + m;
                        outF[idx] = v + b2f(resB[idx]);
                    }
                }
    }
}

// ---------------- scan combine (unchanged) ----------------
__global__ __launch_bounds__(256) void scan_combine(const float* __restrict__ ERe,
                                                    const float* __restrict__ EIm,
                                                    const float* __restrict__ prm,
                                                    float* __restrict__ SinRe,
                                                    float* __restrict__ SinIm){
    int gt = blockIdx.x*256 + threadIdx.x;   // over B*P
    int b = gt / Pz, p = gt % Pz;
    float Ar = prm[4*Pz+p], Ai = prm[5*Pz+p];
    float Sr = 0.f, Si = 0.f;
    for (int c = 0; c < NC; ++c) {
        size_t idx = ((size_t)(b*NC + c))*Pz + p;
        SinRe[idx] = Sr; SinIm[idx] = Si;
        float er = ERe[idx], ei = EIm[idx];
        float nr = Ar*Sr - Ai*Si + er;
        float ni = Ar*Si + Ai*Sr + ei;
        Sr = nr; Si = ni;
    }
}

// ---------------- scan phase2: interleaved, short8 (16B) per row ------------
__global__ __launch_bounds__(64) void scan_phase2(u16* __restrict__ g,
                                                  const float* __restrict__ prm,
                                                  const float* __restrict__ SinRe,
                                                  const float* __restrict__ SinIm){
    int t = blockIdx.x;
    int ph = t & 1; t >>= 1;
    int c  = t % NC;
    int b  = t / NC;
    int p0 = ph*256 + threadIdx.x*4;         // first of 4 states
    int cb = 2*p0;
    size_t base = ((size_t)(b*Lz + c*CL))*1024;
    size_t ci = ((size_t)(b*NC + c))*Pz + p0;
    float Ar[4], Ai[4], fr[4], fi[4], xr[4], xi[4];
    f32x4 sr4 = *(const f32x4*)&SinRe[ci];
    f32x4 si4 = *(const f32x4*)&SinIm[ci];
    #pragma unroll
    for (int j=0;j<4;++j){
        Ar[j]=prm[p0+j]; Ai[j]=prm[Pz+p0+j];
        fr[j]=prm[2*Pz+p0+j]; fi[j]=prm[3*Pz+p0+j];
        xr[j]=sr4[j]; xi[j]=si4[j];
    }
    for (int ll=0; ll<CL; ++ll){
        short8v v8 = *(const short8v*)&g[base + cb];
        short8v o8;
        #pragma unroll
        for (int j=0;j<4;++j){
            float gr = b2f((u16)v8[2*j]), gi = b2f((u16)v8[2*j+1]);
            float br = fr[j]*gr - fi[j]*gi;
            float bi = fr[j]*gi + fi[j]*gr;
            float nr = Ar[j]*xr[j] - Ai[j]*xi[j] + br;
            float ni = Ar[j]*xi[j] + Ai[j]*xr[j] + bi;
            xr[j]=nr; xi[j]=ni;
            o8[2*j]   = (short)f2b(nr);
            o8[2*j+1] = (short)f2b(ni);
        }
        *(short8v*)&g[base + cb] = o8;
        base += 1024;
    }
}

extern "C" void kernel_launch(void* const* d_in, const int* in_sizes, int n_in,
                              void* d_out, int out_size, void* d_ws, size_t ws_size,
                              hipStream_t stream) {
    const float* x        = (const float*)d_in[0];
    const float* ln1_w    = (const float*)d_in[1];
    const float* ln1_b    = (const float*)d_in[2];
    const float* Lre      = (const float*)d_in[3];
    const float* Lim      = (const float*)d_in[4];
    const float* B_re     = (const float*)d_in[5];
    const float* B_im     = (const float*)d_in[6];
    const float* C_re     = (const float*)d_in[7];
    const float* C_im     = (const float*)d_in[8];
    const float* Dv       = (const float*)d_in[9];
    const float* log_step = (const float*)d_in[10];
    const float* ln2_w    = (const float*)d_in[11];
    const float* ln2_b    = (const float*)d_in[12];
    const float* W_enc    = (const float*)d_in[13];
    const float* W_dec    = (const float*)d_in[14];
    float* out = (float*)d_out;

    const size_t NH = (size_t)Nz*Hz;   // 8388608
    char* W = (char*)d_ws;
    u16*   fxb  = (u16*)  (W);                    // [N,512] bf16: fx, later ff
    u16*   g    = (u16*)  (W + NH*2);             // [N,1024] bf16 interleaved: g -> xs
    u16*   hb   = (u16*)  (W + NH*6);             // [N,512] bf16: h
    u16*   fx2b = (u16*)  (W + NH*8);             // [N,512] bf16: fx2
    float* ERe  = (float*)(W + NH*10);
    float* EIm  = ERe + CS;
    float* SinRe= EIm + CS;
    float* SinIm= SinRe + CS;
    float* prm  = SinIm + CS;                     // 6*Pz f32
    u16*   Bcat = (u16*)(prm + 6*Pz);             // [1024,512] interleaved rows
    u16*   Ccat = Bcat + 1024*512;                // [512,1024] interleaved cols
    u16*   Wenc = Ccat + 512*1024;                // [1024,512]
    u16*   Wdec = Wenc + 1024*512;                // [512,512]

    setup_kernel<<<dim3(2), dim3(256), 0, stream>>>(Lre, Lim, log_step, prm);

    cvt_all<<<dim3(6*1024), dim3(256), 0, stream>>>(B_re, B_im, C_re, C_im, W_enc, W_dec,
                                                    Bcat, Ccat, Wenc, Wdec);

    // LN1: x -> fxb (bf16)
    ln_kernel<float><<<dim3(Nz/4), dim3(256), 0, stream>>>(x, ln1_w, ln1_b, fxb);

    // GEMM1 + fused scan-phase1: g (interleaved) + E    grid 64x8 = 512 blocks
    gemmv<512,ESCAN><<<dim3(Nz/256, 1024/128), dim3(512), 0, stream>>>(
        fxb, Bcat, 1024, g, nullptr, nullptr, nullptr, nullptr, prm, ERe, EIm);

    // scan combine + phase2 (in place over g)
    scan_combine<<<dim3((Bz*Pz)/256), dim3(256), 0, stream>>>(ERe, EIm, prm, SinRe, SinIm);
    scan_phase2<<<dim3(Bz*NC*2), dim3(64), 0, stream>>>(g, prm, SinRe, SinIm);

    // GEMM2 (Y): h = gelu(2*(xs@Ccat^T) + D*fx) + fx -> hb   grid 64x4 = 256
    gemmv<1024,EY><<<dim3(Nz/256, 512/128), dim3(512), 0, stream>>>(
        g, Ccat, 512, hb, fxb, Dv, nullptr, nullptr, nullptr, nullptr, nullptr);

    // LN2: hb -> fx2b (bf16)
    ln_kernel<u16><<<dim3(Nz/4), dim3(256), 0, stream>>>(hb, ln2_w, ln2_b, fx2b);

    // GEMM3 + fused GEGLU: ff -> fxb   grid 64x8 = 512
    gemmv<512,EGLU><<<dim3(Nz/256, 1024/128), dim3(512), 0, stream>>>(
        fx2b, Wenc, 1024, fxb, nullptr, nullptr, nullptr, nullptr, nullptr, nullptr, nullptr);

    // GEMM4: out = ff @ Wdec^T + fx2   grid 64x4 = 256
    gemmv<512,ERES><<<dim3(Nz/256, 512/128), dim3(512), 0, stream>>>(
        fxb, Wdec, 512, nullptr, nullptr, nullptr, fx2b, out, nullptr, nullptr, nullptr);
}

// Round 15
// 169.214 us; speedup vs baseline: 1.9081x; 1.0308x over previous
//
#include <hip/hip_runtime.h>
#include <math.h>

// (B,L,H,P) = (4,4096,512,512)
#define Bz 4
#define Lz 4096
#define Hz 512
#define Pz 512
#define Nz (Bz*Lz)          // 16384 rows
#define CL 32               // scan chunk length (halved: more TLP, shorter chains)
#define NC (Lz/CL)          // 128 chunks
#define CS (Bz*NC*Pz)       // 262144 carry slots
#define EPSf 1e-5f

typedef unsigned short u16;
typedef unsigned int   u32;
typedef __attribute__((ext_vector_type(8))) short bf16x8;
typedef __attribute__((ext_vector_type(8))) short short8v;
typedef __attribute__((ext_vector_type(4))) float f32x4;

__device__ __forceinline__ float gelu_exact(float x){
    return 0.5f * x * (1.0f + erff(x * 0.70710678118654752f));
}
__device__ __forceinline__ u16 f2b(float f){
    union { float f; u32 u; } v; v.f = f;
    u32 u = v.u;
    u32 r = (u + 0x7FFFu + ((u >> 16) & 1u)) >> 16;   // RTNE
    return (u16)r;
}
__device__ __forceinline__ float b2f(u16 h){
    union { u32 u; float f; } v; v.u = ((u32)h) << 16; return v.f;
}

__device__ __forceinline__ void gload_lds16(const u16* g, u16* l){
    __builtin_amdgcn_global_load_lds(
        (const __attribute__((address_space(1))) void*)g,
        (__attribute__((address_space(3))) void*)l, 16, 0, 0);
}

// vectorized 8-element row loads (G13)
__device__ __forceinline__ void load8(const float* p, float* v){
    f32x4 a = *(const f32x4*)p, c = *(const f32x4*)(p+4);
    #pragma unroll
    for (int j=0;j<4;++j){ v[j]=a[j]; v[4+j]=c[j]; }
}
__device__ __forceinline__ void load8(const u16* p, float* v){
    short8v s = *(const short8v*)p;
    #pragma unroll
    for (int j=0;j<8;++j) v[j] = b2f((u16)s[j]);
}

// ---------------- setup: per-state SSM params ----------------
__global__ void setup_kernel(const float* __restrict__ Lre, const float* __restrict__ Lim,
                             const float* __restrict__ log_step,
                             float* __restrict__ prm){
    int p = blockIdx.x*blockDim.x + threadIdx.x;
    if (p >= Pz) return;
    float lr = Lre[p], li = Lim[p];
    float dt = expf(log_step[p]);
    float ar = lr*dt, ai = li*dt;
    float e = expf(ar);
    float Abr = e*cosf(ai), Abi = e*sinf(ai);   // Lambda_bar
    prm[p]        = Abr;
    prm[Pz + p]   = Abi;
    float nr = Abr - 1.0f, ni = Abi;
    float d2 = lr*lr + li*li;
    prm[2*Pz + p] = (nr*lr + ni*li)/d2;   // fRe
    prm[3*Pz + p] = (ni*lr - nr*li)/d2;   // fIm
    float arC = ar*(float)CL, aiC = ai*(float)CL;
    float eC = expf(arC);
    prm[4*Pz + p] = eC*cosf(aiC);         // ApowRe = A^CL
    prm[5*Pz + p] = eC*sinf(aiC);         // ApowIm
}

// ---------------- merged weight converts (one launch) ----------------
// Interleaved complex layout: g col 2p = Re_p, 2p+1 = Im_p.
// Bcat row 2p = B_re row p, row 2p+1 = B_im row p  ([1024,512])
// Ccat col 2p = C_re col p, col 2p+1 = -C_im col p ([512,1024])
__global__ __launch_bounds__(256) void cvt_all(const float* __restrict__ B_re,
                                               const float* __restrict__ B_im,
                                               const float* __restrict__ C_re,
                                               const float* __restrict__ C_im,
                                               const float* __restrict__ W_enc,
                                               const float* __restrict__ W_dec,
                                               u16* __restrict__ Bcat,
                                               u16* __restrict__ Ccat,
                                               u16* __restrict__ Wenc,
                                               u16* __restrict__ Wdec){
    const int Q = 512*512;
    int i = blockIdx.x*256 + threadIdx.x;
    if (i < Q){ int p=i>>9, h=i&511; Bcat[(size_t)(2*p)*512 + h]   = f2b(B_re[i]); return; }
    i -= Q;
    if (i < Q){ int p=i>>9, h=i&511; Bcat[(size_t)(2*p+1)*512 + h] = f2b(B_im[i]); return; }
    i -= Q;
    if (i < Q){
        int h = i >> 9, p = i & 511;
        Ccat[(size_t)h*1024 + 2*p]     = f2b(C_re[i]);
        Ccat[(size_t)h*1024 + 2*p + 1] = f2b(-C_im[i]);
        return;
    }
    i -= Q;
    if (i < 2*Q){ Wenc[i] = f2b(W_enc[i]); return; }
    i -= 2*Q;
    Wdec[i] = f2b(W_dec[i]);
}

// ---------------- LayerNorm: wave-per-row, vectorized ----------------
template<typename T>
__global__ __launch_bounds__(256) void ln_kernel(const T* __restrict__ in,
                                                 const float* __restrict__ w,
                                                 const float* __restrict__ b,
                                                 u16* __restrict__ ob){
    int row = blockIdx.x*4 + (threadIdx.x >> 6);
    int l = threadIdx.x & 63;
    float v[8];
    load8(in + (size_t)row*Hz + l*8, v);
    float s = 0.f, q = 0.f;
    #pragma unroll
    for (int j=0;j<8;++j){ s += v[j]; q += v[j]*v[j]; }
    #pragma unroll
    for (int o=32;o;o>>=1){ s += __shfl_xor(s,o); q += __shfl_xor(q,o); }
    float mu = s * (1.0f/512.0f);
    float rs = rsqrtf(q * (1.0f/512.0f) - mu*mu + EPSf);
    short8v o8;
    #pragma unroll
    for (int j=0;j<8;++j){
        int m = l*8 + j;
        o8[j] = (short)f2b((v[j]-mu)*rs*w[m] + b[m]);
    }
    *(short8v*)&ob[(size_t)row*Hz + l*8] = o8;
}

// ============ Counted-vmcnt triple-buffer 256x128 MFMA GEMM ============
// C[N,M] = A[N,K] @ Bw[M,K]^T. BM=256, BN=128, BK=64, 512 threads (8 waves,
// 4M x 2N; per-wave 64x64 -> acc[4][4], 32 MFMA + 16 ds_read_b128 per K-tile).
// LDS: 3 buffers x (A 32KB + B 16KB) = 144KB -> 1 block/CU, 2 waves/SIMD.
// Per K-tile: vmcnt(6) [tile T landed; T+1's 6 loads/thread in flight] ->
// s_barrier -> stage tile T+2 into buf[(T+2)%3] -> ds_read + 32 MFMA.
// vmcnt NEVER drains to 0 mid-loop (T4); a staged tile gets 2 full K-tiles
// of cover. WAR-safe: buf[(T+2)%3] == buf[(T-1)%3], whose reads all drained
// before each wave passed barrier_T. [R14-proven: broke the ~50us plateau]
#define EY    1
#define ERES  2
#define EGLU  3
#define ESCAN 4

#define ATW (256*64)
#define BTW (128*64)
#define TBW (ATW+BTW)

// A-tile 256x64 (32KB): 4 gload_lds/thread. Verified 0-conflict swizzle pair.
__device__ __forceinline__ void stageA256v(const u16* __restrict__ src, int ld,
                                           int row0, int kt, u16* lds){
    int lane = threadIdx.x & 63, w = threadIdx.x >> 6;
    #pragma unroll
    for (int q=0;q<4;++q){
        int c = w + q*8;                               // 1KB chunk, 0..31 (8 rows)
        int r = c*8 + (lane >> 3);                     // row 0..255
        int colE = 8*((lane & 7) ^ ((lane >> 3) & 7));
        gload_lds16(src + (size_t)(row0 + r)*ld + kt + colE, lds + c*512);
    }
}
// B-tile 128x64 (16KB): 2 gload_lds/thread
__device__ __forceinline__ void stageB128v(const u16* __restrict__ src, int ld,
                                           int row0, int kt, u16* lds){
    int lane = threadIdx.x & 63, w = threadIdx.x >> 6;
    #pragma unroll
    for (int q=0;q<2;++q){
        int c = w + q*8;                               // 0..15
        int r = c*8 + (lane >> 3);                     // row 0..127
        int colE = 8*((lane & 7) ^ ((lane >> 3) & 7));
        gload_lds16(src + (size_t)(row0 + r)*ld + kt + colE, lds + c*512);
    }
}
// GEGLU virtual-B: 16-row frags alternate a-rows / g-rows of Wenc (K=512)
__device__ __forceinline__ void stageBglu(const u16* __restrict__ Wenc, int fb,
                                          int kt, u16* lds){
    int lane = threadIdx.x & 63, w = threadIdx.x >> 6;
    #pragma unroll
    for (int q=0;q<2;++q){
        int c = w + q*8;
        int v = c*8 + (lane >> 3);                     // virtual row 0..127
        int vf = v >> 4, r = v & 15;
        int grow = ((vf & 1) ? 512 : 0) + fb + (vf >> 1)*16 + r;
        int colE = 8*((lane & 7) ^ ((lane >> 3) & 7));
        gload_lds16(Wenc + (size_t)grow*512 + kt + colE, lds + c*512);
    }
}

template<int K, int EPI>
__global__ __launch_bounds__(512)
void gemmv(const u16* __restrict__ A, const u16* __restrict__ Bw, int M,
           u16* __restrict__ outB,
           const u16* __restrict__ fxB,        // EY
           const float* __restrict__ Dv,       // EY
           const u16* __restrict__ resB,       // ERES
           float* __restrict__ outF,           // ERES
           const float* __restrict__ prm,      // ESCAN
           float* __restrict__ ERe,            // ESCAN
           float* __restrict__ EIm)            // ESCAN
{
    constexpr int NT = K/64;
    __shared__ u16 LDS[3*TBW];   // 144KB

    int nx = gridDim.x, ny = gridDim.y;
    int nwg = nx*ny;
    int lid = blockIdx.x + blockIdx.y*nx;
    int cpx = nwg >> 3;
    int gdx = (lid & 7)*cpx + (lid >> 3);
    int n0 = (gdx / ny) * 256;
    int mb = gdx % ny;
    int m0 = mb * 128;          // output-col block (virtual for EGLU)
    int fb = mb * 64;           // EGLU ff-col base

    int l = threadIdx.x & 63;
    int w = threadIdx.x >> 6;
    int wm = w >> 1, wn = w & 1;
    int rb = wm*64, cb = wn*64;
    int lrow  = l & 15;
    int lcol0 = ((l >> 4)*8) ^ ((l & 7) << 3);
    int lcol1 = lcol0 ^ 32;

    f32x4 acc[4][4];
    #pragma unroll
    for (int i=0;i<4;++i)
        #pragma unroll
        for (int j=0;j<4;++j) acc[i][j] = (f32x4)(0.f);

    // prologue: stage tiles 0 and 1 (12 loads/thread outstanding)
    stageA256v(A, K, n0, 0, &LDS[0]);
    if (EPI==EGLU) stageBglu(Bw, fb, 0, &LDS[ATW]); else stageB128v(Bw, K, m0, 0, &LDS[ATW]);
    stageA256v(A, K, n0, 64, &LDS[TBW]);
    if (EPI==EGLU) stageBglu(Bw, fb, 64, &LDS[TBW+ATW]); else stageB128v(Bw, K, m0, 64, &LDS[TBW+ATW]);

    for (int T=0; T<NT; ++T){
        if (T == NT-1){ asm volatile("s_waitcnt vmcnt(0)" ::: "memory"); }
        else          { asm volatile("s_waitcnt vmcnt(6)" ::: "memory"); }
        __builtin_amdgcn_s_barrier();
        if (T+2 < NT){
            u16* buf = &LDS[((T+2)%3)*TBW];
            int ktn = (T+2)*64;
            stageA256v(A, K, n0, ktn, buf);
            if (EPI==EGLU) stageBglu(Bw, fb, ktn, buf+ATW); else stageB128v(Bw, K, m0, ktn, buf+ATW);
        }
        const u16* Ab = &LDS[(T%3)*TBW];
        const u16* Bb = Ab + ATW;
        bf16x8 a0[4], a1[4], b0[4], b1[4];
        #pragma unroll
        for (int f=0; f<4; ++f){
            a0[f] = *(const bf16x8*)&Ab[(rb + f*16 + lrow)*64 + lcol0];
            a1[f] = *(const bf16x8*)&Ab[(rb + f*16 + lrow)*64 + lcol1];
        }
        #pragma unroll
        for (int g=0; g<4; ++g){
            b0[g] = *(const bf16x8*)&Bb[(cb + g*16 + lrow)*64 + lcol0];
            b1[g] = *(const bf16x8*)&Bb[(cb + g*16 + lrow)*64 + lcol1];
        }
        __builtin_amdgcn_s_setprio(1);
        #pragma unroll
        for (int f=0; f<4; ++f)
            #pragma unroll
            for (int g=0; g<4; ++g){
                acc[f][g] = __builtin_amdgcn_mfma_f32_16x16x32_bf16(a0[f], b0[g], acc[f][g], 0,0,0);
                acc[f][g] = __builtin_amdgcn_mfma_f32_16x16x32_bf16(a1[f], b1[g], acc[f][g], 0,0,0);
            }
        __builtin_amdgcn_s_setprio(0);
    }

    // epilogue: C layout col=lane&15, row=(lane>>4)*4+q
    int er = (l >> 4) * 4;
    int ec = l & 15;

    if (EPI == ESCAN){
        u16* gt = (u16*)LDS;   // alias staging (dead); [256][128] u16 = 64KB
        __syncthreads();
        #pragma unroll
        for (int fm=0; fm<4; ++fm)
            #pragma unroll
            for (int g=0; g<4; ++g)
                #pragma unroll
                for (int q=0; q<4; ++q){
                    int rr = rb + fm*16 + er + q;
                    int cc = cb + g*16 + ec;
                    u16 hv = f2b(acc[fm][g][q]);
                    outB[(size_t)(n0 + rr)*M + (m0 + cc)] = hv;
                    gt[rr*128 + cc] = hv;
                }
        __syncthreads();
        // fused scan phase1 @ CL=32: ALL 512 threads, (p = tid&63, h = tid>>6),
        // each scans 32 rows of its chunk
        int tid = threadIdx.x;
        int p = tid & 63, h = tid >> 6;          // h 0..7 (8 chunks of 32 rows)
        int P = (m0 >> 1) + p;
        int b = n0 >> 12;
        int c = ((n0 & 4095) >> 5) + h;
        float Ar = prm[P], Ai = prm[Pz+P];
        float fre = prm[2*Pz+P], fim = prm[3*Pz+P];
        float xr = 0.f, xi = 0.f;
        int base = h*32*128 + 2*p;
        #pragma unroll 8
        for (int r = 0; r < 32; ++r){
            u32 v = *(const u32*)&gt[base + r*128];
            float gr = b2f((u16)(v & 0xffff));
            float gi = b2f((u16)(v >> 16));
            float br = fre*gr - fim*gi;
            float bi = fre*gi + fim*gr;
            float nr2 = Ar*xr - Ai*xi + br;
            float ni2 = Ar*xi + Ai*xr + bi;
            xr = nr2; xi = ni2;
        }
        size_t ci = ((size_t)(b*NC + c))*Pz + P;
        ERe[ci] = xr; EIm[ci] = xi;
    } else if (EPI == EGLU){
        #pragma unroll
        for (int fm=0; fm<4; ++fm)
            #pragma unroll
            for (int pr=0; pr<2; ++pr)
                #pragma unroll
                for (int q=0; q<4; ++q){
                    int n = n0 + rb + fm*16 + er + q;
                    int col = fb + (wn*2 + pr)*16 + ec;
                    float ffv = acc[fm][2*pr][q] * gelu_exact(acc[fm][2*pr+1][q]);
                    outB[(size_t)n*Hz + col] = f2b(ffv);
                }
    } else {
        #pragma unroll
        for (int fm=0; fm<4; ++fm)
            #pragma unroll
            for (int g=0; g<4; ++g)
                #pragma unroll
                for (int q=0; q<4; ++q){
                    int n = n0 + rb + fm*16 + er + q;
                    int m = m0 + cb + g*16 + ec;
                    float v = acc[fm][g][q];
                    if (EPI == EY){
                        size_t idx = (size_t)n*Hz + m;
                        float fxv = b2f(fxB[idx]);
                        float y = 2.0f*v + Dv[m]*fxv;
                        outB[idx] = f2b(gelu_exact(y) + fxv);
                    } else {  // ERES
                        size_t idx = (size_t)n*Hz + m;
                        outF[idx] = v + b2f(resB[idx]);
                    }
                }
    }
}

// ---------------- scan combine (NC=128 chunks) ----------------
__global__ __launch_bounds__(256) void scan_combine(const float* __restrict__ ERe,
                                                    const float* __restrict__ EIm,
                                                    const float* __restrict__ prm,
                                                    float* __restrict__ SinRe,
                                                    float* __restrict__ SinIm){
    int gt = blockIdx.x*256 + threadIdx.x;   // over B*P
    int b = gt / Pz, p = gt % Pz;
    float Ar = prm[4*Pz+p], Ai = prm[5*Pz+p];
    float Sr = 0.f, Si = 0.f;
    for (int c = 0; c < NC; ++c) {
        size_t idx = ((size_t)(b*NC + c))*Pz + p;
        SinRe[idx] = Sr; SinIm[idx] = Si;
        float er = ERe[idx], ei = EIm[idx];
        float nr = Ar*Sr - Ai*Si + er;
        float ni = Ar*Si + Ai*Sr + ei;
        Sr = nr; Si = ni;
    }
}

// ---------------- scan phase2: interleaved, short8 (16B) per row ------------
// CL=32: grid Bz*NC*2 = 1024 blocks x 64 thr (4 waves/CU), 32-iter chains.
__global__ __launch_bounds__(64) void scan_phase2(u16* __restrict__ g,
                                                  const float* __restrict__ prm,
                                                  const float* __restrict__ SinRe,
                                                  const float* __restrict__ SinIm){
    int t = blockIdx.x;
    int ph = t & 1; t >>= 1;
    int c  = t % NC;
    int b  = t / NC;
    int p0 = ph*256 + threadIdx.x*4;         // first of 4 states
    int cbi = 2*p0;
    size_t base = ((size_t)(b*Lz + c*CL))*1024;
    size_t ci = ((size_t)(b*NC + c))*Pz + p0;
    float Ar[4], Ai[4], fr[4], fi[4], xr[4], xi[4];
    f32x4 sr4 = *(const f32x4*)&SinRe[ci];
    f32x4 si4 = *(const f32x4*)&SinIm[ci];
    #pragma unroll
    for (int j=0;j<4;++j){
        Ar[j]=prm[p0+j]; Ai[j]=prm[Pz+p0+j];
        fr[j]=prm[2*Pz+p0+j]; fi[j]=prm[3*Pz+p0+j];
        xr[j]=sr4[j]; xi[j]=si4[j];
    }
    for (int ll=0; ll<CL; ++ll){
        short8v v8 = *(const short8v*)&g[base + cbi];
        short8v o8;
        #pragma unroll
        for (int j=0;j<4;++j){
            float gr = b2f((u16)v8[2*j]), gi = b2f((u16)v8[2*j+1]);
            float br = fr[j]*gr - fi[j]*gi;
            float bi = fr[j]*gi + fi[j]*gr;
            float nr = Ar[j]*xr[j] - Ai[j]*xi[j] + br;
            float ni = Ar[j]*xi[j] + Ai[j]*xr[j] + bi;
            xr[j]=nr; xi[j]=ni;
            o8[2*j]   = (short)f2b(nr);
            o8[2*j+1] = (short)f2b(ni);
        }
        *(short8v*)&g[base + cbi] = o8;
        base += 1024;
    }
}

extern "C" void kernel_launch(void* const* d_in, const int* in_sizes, int n_in,
                              void* d_out, int out_size, void* d_ws, size_t ws_size,
                              hipStream_t stream) {
    const float* x        = (const float*)d_in[0];
    const float* ln1_w    = (const float*)d_in[1];
    const float* ln1_b    = (const float*)d_in[2];
    const float* Lre      = (const float*)d_in[3];
    const float* Lim      = (const float*)d_in[4];
    const float* B_re     = (const float*)d_in[5];
    const float* B_im     = (const float*)d_in[6];
    const float* C_re     = (const float*)d_in[7];
    const float* C_im     = (const float*)d_in[8];
    const float* Dv       = (const float*)d_in[9];
    const float* log_step = (const float*)d_in[10];
    const float* ln2_w    = (const float*)d_in[11];
    const float* ln2_b    = (const float*)d_in[12];
    const float* W_enc    = (const float*)d_in[13];
    const float* W_dec    = (const float*)d_in[14];
    float* out = (float*)d_out;

    const size_t NH = (size_t)Nz*Hz;   // 8388608
    char* W = (char*)d_ws;
    u16*   fxb  = (u16*)  (W);                    // [N,512] bf16: fx, later ff
    u16*   g    = (u16*)  (W + NH*2);             // [N,1024] bf16 interleaved: g -> xs
    u16*   hb   = (u16*)  (W + NH*6);             // [N,512] bf16: h
    u16*   fx2b = (u16*)  (W + NH*8);             // [N,512] bf16: fx2
    float* ERe  = (float*)(W + NH*10);
    float* EIm  = ERe + CS;
    float* SinRe= EIm + CS;
    float* SinIm= SinRe + CS;
    float* prm  = SinIm + CS;                     // 6*Pz f32
    u16*   Bcat = (u16*)(prm + 6*Pz);             // [1024,512] interleaved rows
    u16*   Ccat = Bcat + 1024*512;                // [512,1024] interleaved cols
    u16*   Wenc = Ccat + 512*1024;                // [1024,512]
    u16*   Wdec = Wenc + 1024*512;                // [512,512]

    setup_kernel<<<dim3(2), dim3(256), 0, stream>>>(Lre, Lim, log_step, prm);

    cvt_all<<<dim3(6*1024), dim3(256), 0, stream>>>(B_re, B_im, C_re, C_im, W_enc, W_dec,
                                                    Bcat, Ccat, Wenc, Wdec);

    // LN1: x -> fxb (bf16)
    ln_kernel<float><<<dim3(Nz/4), dim3(256), 0, stream>>>(x, ln1_w, ln1_b, fxb);

    // GEMM1 + fused scan-phase1: g (interleaved) + E    grid 64x8 = 512 blocks
    gemmv<512,ESCAN><<<dim3(Nz/256, 1024/128), dim3(512), 0, stream>>>(
        fxb, Bcat, 1024, g, nullptr, nullptr, nullptr, nullptr, prm, ERe, EIm);

    // scan combine + phase2 (in place over g)
    scan_combine<<<dim3((Bz*Pz)/256), dim3(256), 0, stream>>>(ERe, EIm, prm, SinRe, SinIm);
    scan_phase2<<<dim3(Bz*NC*2), dim3(64), 0, stream>>>(g, prm, SinRe, SinIm);

    // GEMM2 (Y): h = gelu(2*(xs@Ccat^T) + D*fx) + fx -> hb   grid 64x4 = 256
    gemmv<1024,EY><<<dim3(Nz/256, 512/128), dim3(512), 0, stream>>>(
        g, Ccat, 512, hb, fxb, Dv, nullptr, nullptr, nullptr, nullptr, nullptr);

    // LN2: hb -> fx2b (bf16)
    ln_kernel<u16><<<dim3(Nz/4), dim3(256), 0, stream>>>(hb, ln2_w, ln2_b, fx2b);

    // GEMM3 + fused GEGLU: ff -> fxb   grid 64x8 = 512
    gemmv<512,EGLU><<<dim3(Nz/256, 1024/128), dim3(512), 0, stream>>>(
        fx2b, Wenc, 1024, fxb, nullptr, nullptr, nullptr, nullptr, nullptr, nullptr, nullptr);

    // GEMM4: out = ff @ Wdec^T + fx2   grid 64x4 = 256
    gemmv<512,ERES><<<dim3(Nz/256, 512/128), dim3(512), 0, stream>>>(
        fxb, Wdec, 512, nullptr, nullptr, nullptr, fx2b, out, nullptr, nullptr, nullptr);
}

// Round 16
// 166.722 us; speedup vs baseline: 1.9366x; 1.0150x over previous
//
#include <hip/hip_runtime.h>
#include <math.h>

// (B,L,H,P) = (4,4096,512,512)
#define Bz 4
#define Lz 4096
#define Hz 512
#define Pz 512
#define Nz (Bz*Lz)          // 16384 rows
#define CL 32               // scan chunk length
#define NC (Lz/CL)          // 128 chunks
#define CS (Bz*NC*Pz)       // 262144 carry slots
#define EPSf 1e-5f

typedef unsigned short u16;
typedef unsigned int   u32;
typedef __attribute__((ext_vector_type(8))) short bf16x8;
typedef __attribute__((ext_vector_type(8))) short short8v;
typedef __attribute__((ext_vector_type(4))) float f32x4;

__device__ __forceinline__ float gelu_exact(float x){
    return 0.5f * x * (1.0f + erff(x * 0.70710678118654752f));
}
__device__ __forceinline__ u16 f2b(float f){
    union { float f; u32 u; } v; v.f = f;
    u32 u = v.u;
    u32 r = (u + 0x7FFFu + ((u >> 16) & 1u)) >> 16;   // RTNE
    return (u16)r;
}
__device__ __forceinline__ float b2f(u16 h){
    union { u32 u; float f; } v; v.u = ((u32)h) << 16; return v.f;
}

__device__ __forceinline__ void gload_lds16(const u16* g, u16* l){
    __builtin_amdgcn_global_load_lds(
        (const __attribute__((address_space(1))) void*)g,
        (__attribute__((address_space(3))) void*)l, 16, 0, 0);
}

// vectorized 8-element row loads (G13)
__device__ __forceinline__ void load8(const float* p, float* v){
    f32x4 a = *(const f32x4*)p, c = *(const f32x4*)(p+4);
    #pragma unroll
    for (int j=0;j<4;++j){ v[j]=a[j]; v[4+j]=c[j]; }
}
__device__ __forceinline__ void load8(const u16* p, float* v){
    short8v s = *(const short8v*)p;
    #pragma unroll
    for (int j=0;j<8;++j) v[j] = b2f((u16)s[j]);
}

// ---------------- merged weight converts + SSM setup (one launch) ----------
// Interleaved complex layout: g col 2p = Re_p, 2p+1 = Im_p.
// Bcat row 2p = B_re row p, row 2p+1 = B_im row p  ([1024,512])
// Ccat col 2p = C_re col p, col 2p+1 = -C_im col p ([512,1024])
// Blocks >= 6*1024 compute the per-state SSM params (prm).
__global__ __launch_bounds__(256) void cvt_all(const float* __restrict__ B_re,
                                               const float* __restrict__ B_im,
                                               const float* __restrict__ C_re,
                                               const float* __restrict__ C_im,
                                               const float* __restrict__ W_enc,
                                               const float* __restrict__ W_dec,
                                               const float* __restrict__ Lre,
                                               const float* __restrict__ Lim,
                                               const float* __restrict__ log_step,
                                               u16* __restrict__ Bcat,
                                               u16* __restrict__ Ccat,
                                               u16* __restrict__ Wenc,
                                               u16* __restrict__ Wdec,
                                               float* __restrict__ prm){
    const int Q = 512*512;
    int blk = blockIdx.x;
    if (blk >= 6*1024){   // setup part
        int p = (blk - 6*1024)*256 + threadIdx.x;
        if (p >= Pz) return;
        float lr = Lre[p], li = Lim[p];
        float dt = expf(log_step[p]);
        float ar = lr*dt, ai = li*dt;
        float e = expf(ar);
        float Abr = e*cosf(ai), Abi = e*sinf(ai);   // Lambda_bar
        prm[p]        = Abr;
        prm[Pz + p]   = Abi;
        float nr = Abr - 1.0f, ni = Abi;
        float d2 = lr*lr + li*li;
        prm[2*Pz + p] = (nr*lr + ni*li)/d2;   // fRe
        prm[3*Pz + p] = (ni*lr - nr*li)/d2;   // fIm
        float arC = ar*(float)CL, aiC = ai*(float)CL;
        float eC = expf(arC);
        prm[4*Pz + p] = eC*cosf(aiC);         // ApowRe = A^CL
        prm[5*Pz + p] = eC*sinf(aiC);         // ApowIm
        return;
    }
    int i = blk*256 + threadIdx.x;
    if (i < Q){ int p=i>>9, h=i&511; Bcat[(size_t)(2*p)*512 + h]   = f2b(B_re[i]); return; }
    i -= Q;
    if (i < Q){ int p=i>>9, h=i&511; Bcat[(size_t)(2*p+1)*512 + h] = f2b(B_im[i]); return; }
    i -= Q;
    if (i < Q){
        int h = i >> 9, p = i & 511;
        Ccat[(size_t)h*1024 + 2*p]     = f2b(C_re[i]);
        Ccat[(size_t)h*1024 + 2*p + 1] = f2b(-C_im[i]);
        return;
    }
    i -= Q;
    if (i < 2*Q){ Wenc[i] = f2b(W_enc[i]); return; }
    i -= 2*Q;
    Wdec[i] = f2b(W_dec[i]);
}

// ---------------- LayerNorm: wave-per-row, vectorized ----------------
template<typename T>
__global__ __launch_bounds__(256) void ln_kernel(const T* __restrict__ in,
                                                 const float* __restrict__ w,
                                                 const float* __restrict__ b,
                                                 u16* __restrict__ ob){
    int row = blockIdx.x*4 + (threadIdx.x >> 6);
    int l = threadIdx.x & 63;
    float v[8];
    load8(in + (size_t)row*Hz + l*8, v);
    float s = 0.f, q = 0.f;
    #pragma unroll
    for (int j=0;j<8;++j){ s += v[j]; q += v[j]*v[j]; }
    #pragma unroll
    for (int o=32;o;o>>=1){ s += __shfl_xor(s,o); q += __shfl_xor(q,o); }
    float mu = s * (1.0f/512.0f);
    float rs = rsqrtf(q * (1.0f/512.0f) - mu*mu + EPSf);
    short8v o8;
    #pragma unroll
    for (int j=0;j<8;++j){
        int m = l*8 + j;
        o8[j] = (short)f2b((v[j]-mu)*rs*w[m] + b[m]);
    }
    *(short8v*)&ob[(size_t)row*Hz + l*8] = o8;
}

// ============ Counted-vmcnt triple-buffer 256x128 MFMA GEMM ============
// C[N,M] = A[N,K] @ Bw[M,K]^T. BM=256, BN=128, BK=64, 512 threads (8 waves,
// 4M x 2N; per-wave 64x64 -> acc[4][4], 32 MFMA + 16 ds_read_b128 per K-tile).
// LDS: 3 buffers x (A 32KB + B 16KB) = 144KB -> 1 block/CU, 2 waves/SIMD.
// Per K-tile: vmcnt(6) -> s_barrier -> stage tile T+2 -> ds_read + 32 MFMA.
// vmcnt NEVER drains to 0 mid-loop (T4). [R14-proven: broke the ~50us plateau]
// EGLU additionally runs TWO 256-row panels per block in one seamless 16-tile
// pipeline (B-tiles identical across panels) — one prologue fill, one tail.
#define EY    1
#define ERES  2
#define EGLU  3
#define ESCAN 4

#define ATW (256*64)
#define BTW (128*64)
#define TBW (ATW+BTW)

// A-tile 256x64 (32KB): 4 gload_lds/thread. Verified 0-conflict swizzle pair.
__device__ __forceinline__ void stageA256v(const u16* __restrict__ src, int ld,
                                           int row0, int kt, u16* lds){
    int lane = threadIdx.x & 63, w = threadIdx.x >> 6;
    #pragma unroll
    for (int q=0;q<4;++q){
        int c = w + q*8;                               // 1KB chunk, 0..31 (8 rows)
        int r = c*8 + (lane >> 3);                     // row 0..255
        int colE = 8*((lane & 7) ^ ((lane >> 3) & 7));
        gload_lds16(src + (size_t)(row0 + r)*ld + kt + colE, lds + c*512);
    }
}
// B-tile 128x64 (16KB): 2 gload_lds/thread
__device__ __forceinline__ void stageB128v(const u16* __restrict__ src, int ld,
                                           int row0, int kt, u16* lds){
    int lane = threadIdx.x & 63, w = threadIdx.x >> 6;
    #pragma unroll
    for (int q=0;q<2;++q){
        int c = w + q*8;                               // 0..15
        int r = c*8 + (lane >> 3);                     // row 0..127
        int colE = 8*((lane & 7) ^ ((lane >> 3) & 7));
        gload_lds16(src + (size_t)(row0 + r)*ld + kt + colE, lds + c*512);
    }
}
// GEGLU virtual-B: 16-row frags alternate a-rows / g-rows of Wenc (K=512)
__device__ __forceinline__ void stageBglu(const u16* __restrict__ Wenc, int fb,
                                          int kt, u16* lds){
    int lane = threadIdx.x & 63, w = threadIdx.x >> 6;
    #pragma unroll
    for (int q=0;q<2;++q){
        int c = w + q*8;
        int v = c*8 + (lane >> 3);                     // virtual row 0..127
        int vf = v >> 4, r = v & 15;
        int grow = ((vf & 1) ? 512 : 0) + fb + (vf >> 1)*16 + r;
        int colE = 8*((lane & 7) ^ ((lane >> 3) & 7));
        gload_lds16(Wenc + (size_t)grow*512 + kt + colE, lds + c*512);
    }
}

template<int K, int EPI>
__global__ __launch_bounds__(512)
void gemmv(const u16* __restrict__ A, const u16* __restrict__ Bw, int M,
           u16* __restrict__ outB,
           const u16* __restrict__ fxB,        // EY
           const float* __restrict__ Dv,       // EY
           const u16* __restrict__ resB,       // ERES
           float* __restrict__ outF,           // ERES
           const float* __restrict__ prm,      // ESCAN
           float* __restrict__ ERe,            // ESCAN
           float* __restrict__ EIm)            // ESCAN
{
    constexpr int NT = K/64;
    constexpr int NP = (EPI==EGLU) ? 2 : 1;     // panels per block
    constexpr int TT = NT*NP;                    // total tiles in pipeline
    __shared__ u16 LDS[3*TBW];   // 144KB

    int nx = gridDim.x, ny = gridDim.y;
    int nwg = nx*ny;
    int lid = blockIdx.x + blockIdx.y*nx;
    int cpx = nwg >> 3;
    int gdx = (lid & 7)*cpx + (lid >> 3);
    int n0 = (gdx / ny) * 256 * NP;
    int mb = gdx % ny;
    int m0 = mb * 128;          // output-col block (virtual for EGLU)
    int fb = mb * 64;           // EGLU ff-col base

    int l = threadIdx.x & 63;
    int w = threadIdx.x >> 6;
    int wm = w >> 1, wn = w & 1;
    int rb = wm*64, cb = wn*64;
    int lrow  = l & 15;
    int lcol0 = ((l >> 4)*8) ^ ((l & 7) << 3);
    int lcol1 = lcol0 ^ 32;
    int er = (l >> 4) * 4;
    int ec = l & 15;

    f32x4 acc[4][4];
    #pragma unroll
    for (int i=0;i<4;++i)
        #pragma unroll
        for (int j=0;j<4;++j) acc[i][j] = (f32x4)(0.f);

    // prologue: stage tiles 0 and 1 (12 loads/thread outstanding)
    stageA256v(A, K, n0, 0, &LDS[0]);
    if (EPI==EGLU) stageBglu(Bw, fb, 0, &LDS[ATW]); else stageB128v(Bw, K, m0, 0, &LDS[ATW]);
    stageA256v(A, K, n0, 64, &LDS[TBW]);
    if (EPI==EGLU) stageBglu(Bw, fb, 64, &LDS[TBW+ATW]); else stageB128v(Bw, K, m0, 64, &LDS[TBW+ATW]);

    for (int T=0; T<TT; ++T){
        if (T == TT-1){ asm volatile("s_waitcnt vmcnt(0)" ::: "memory"); }
        else          { asm volatile("s_waitcnt vmcnt(6)" ::: "memory"); }
        __builtin_amdgcn_s_barrier();
        if (T+2 < TT){
            u16* buf = &LDS[((T+2)%3)*TBW];
            int t2 = T+2;
            int ktn = (t2 % NT)*64;
            int rowA = n0 + (t2/NT)*256;
            stageA256v(A, K, rowA, ktn, buf);
            if (EPI==EGLU) stageBglu(Bw, fb, ktn, buf+ATW); else stageB128v(Bw, K, m0, ktn, buf+ATW);
        }
        const u16* Ab = &LDS[(T%3)*TBW];
        const u16* Bb = Ab + ATW;
        bf16x8 a0[4], a1[4], b0[4], b1[4];
        #pragma unroll
        for (int f=0; f<4; ++f){
            a0[f] = *(const bf16x8*)&Ab[(rb + f*16 + lrow)*64 + lcol0];
            a1[f] = *(const bf16x8*)&Ab[(rb + f*16 + lrow)*64 + lcol1];
        }
        #pragma unroll
        for (int g=0; g<4; ++g){
            b0[g] = *(const bf16x8*)&Bb[(cb + g*16 + lrow)*64 + lcol0];
            b1[g] = *(const bf16x8*)&Bb[(cb + g*16 + lrow)*64 + lcol1];
        }
        __builtin_amdgcn_s_setprio(1);
        #pragma unroll
        for (int f=0; f<4; ++f)
            #pragma unroll
            for (int g=0; g<4; ++g){
                acc[f][g] = __builtin_amdgcn_mfma_f32_16x16x32_bf16(a0[f], b0[g], acc[f][g], 0,0,0);
                acc[f][g] = __builtin_amdgcn_mfma_f32_16x16x32_bf16(a1[f], b1[g], acc[f][g], 0,0,0);
            }
        __builtin_amdgcn_s_setprio(0);
        // EGLU panel-0 epilogue mid-pipeline (no LDS use; pipeline keeps flowing)
        if (EPI==EGLU && NP==2 && T == NT-1){
            #pragma unroll
            for (int fm=0; fm<4; ++fm)
                #pragma unroll
                for (int pr=0; pr<2; ++pr)
                    #pragma unroll
                    for (int q=0; q<4; ++q){
                        int n = n0 + rb + fm*16 + er + q;
                        int col = fb + (wn*2 + pr)*16 + ec;
                        float ffv = acc[fm][2*pr][q] * gelu_exact(acc[fm][2*pr+1][q]);
                        outB[(size_t)n*Hz + col] = f2b(ffv);
                    }
            #pragma unroll
            for (int i=0;i<4;++i)
                #pragma unroll
                for (int j=0;j<4;++j) acc[i][j] = (f32x4)(0.f);
        }
    }

    if (EPI == ESCAN){
        u16* gt = (u16*)LDS;   // alias staging (dead); [256][128] u16 = 64KB
        __syncthreads();
        #pragma unroll
        for (int fm=0; fm<4; ++fm)
            #pragma unroll
            for (int g=0; g<4; ++g)
                #pragma unroll
                for (int q=0; q<4; ++q){
                    int rr = rb + fm*16 + er + q;
                    int cc = cb + g*16 + ec;
                    u16 hv = f2b(acc[fm][g][q]);
                    outB[(size_t)(n0 + rr)*M + (m0 + cc)] = hv;
                    gt[rr*128 + cc] = hv;
                }
        __syncthreads();
        // fused scan phase1 @ CL=32: ALL 512 threads (p = tid&63, h = tid>>6)
        int tid = threadIdx.x;
        int p = tid & 63, h = tid >> 6;          // h 0..7 (8 chunks of 32 rows)
        int P = (m0 >> 1) + p;
        int b = n0 >> 12;
        int c = ((n0 & 4095) >> 5) + h;
        float Ar = prm[P], Ai = prm[Pz+P];
        float fre = prm[2*Pz+P], fim = prm[3*Pz+P];
        float xr = 0.f, xi = 0.f;
        int base = h*32*128 + 2*p;
        #pragma unroll 8
        for (int r = 0; r < 32; ++r){
            u32 v = *(const u32*)&gt[base + r*128];
            float gr = b2f((u16)(v & 0xffff));
            float gi = b2f((u16)(v >> 16));
            float br = fre*gr - fim*gi;
            float bi = fre*gi + fim*gr;
            float nr2 = Ar*xr - Ai*xi + br;
            float ni2 = Ar*xi + Ai*xr + bi;
            xr = nr2; xi = ni2;
        }
        size_t ci = ((size_t)(b*NC + c))*Pz + P;
        ERe[ci] = xr; EIm[ci] = xi;
    } else if (EPI == EGLU){
        int nb = n0 + (NP-1)*256;   // last panel
        #pragma unroll
        for (int fm=0; fm<4; ++fm)
            #pragma unroll
            for (int pr=0; pr<2; ++pr)
                #pragma unroll
                for (int q=0; q<4; ++q){
                    int n = nb + rb + fm*16 + er + q;
                    int col = fb + (wn*2 + pr)*16 + ec;
                    float ffv = acc[fm][2*pr][q] * gelu_exact(acc[fm][2*pr+1][q]);
                    outB[(size_t)n*Hz + col] = f2b(ffv);
                }
    } else {
        #pragma unroll
        for (int fm=0; fm<4; ++fm)
            #pragma unroll
            for (int g=0; g<4; ++g)
                #pragma unroll
                for (int q=0; q<4; ++q){
                    int n = n0 + rb + fm*16 + er + q;
                    int m = m0 + cb + g*16 + ec;
                    float v = acc[fm][g][q];
                    if (EPI == EY){
                        size_t idx = (size_t)n*Hz + m;
                        float fxv = b2f(fxB[idx]);
                        float y = 2.0f*v + Dv[m]*fxv;
                        outB[idx] = f2b(gelu_exact(y) + fxv);
                    } else {  // ERES
                        size_t idx = (size_t)n*Hz + m;
                        outF[idx] = v + b2f(resB[idx]);
                    }
                }
    }
}

// ---------------- scan combine (NC=128 chunks; 32 blocks x 64 thr) ----------
__global__ __launch_bounds__(64) void scan_combine(const float* __restrict__ ERe,
                                                   const float* __restrict__ EIm,
                                                   const float* __restrict__ prm,
                                                   float* __restrict__ SinRe,
                                                   float* __restrict__ SinIm){
    int gt = blockIdx.x*64 + threadIdx.x;   // over B*P
    int b = gt / Pz, p = gt % Pz;
    float Ar = prm[4*Pz+p], Ai = prm[5*Pz+p];
    float Sr = 0.f, Si = 0.f;
    for (int c = 0; c < NC; ++c) {
        size_t idx = ((size_t)(b*NC + c))*Pz + p;
        SinRe[idx] = Sr; SinIm[idx] = Si;
        float er = ERe[idx], ei = EIm[idx];
        float nr = Ar*Sr - Ai*Si + er;
        float ni = Ar*Si + Ai*Sr + ei;
        Sr = nr; Si = ni;
    }
}

// ---------------- scan phase2: interleaved, short8 (16B) per row ------------
// CL=32: grid Bz*NC*2 = 1024 blocks x 64 thr, 32-iter chains.
__global__ __launch_bounds__(64) void scan_phase2(u16* __restrict__ g,
                                                  const float* __restrict__ prm,
                                                  const float* __restrict__ SinRe,
                                                  const float* __restrict__ SinIm){
    int t = blockIdx.x;
    int ph = t & 1; t >>= 1;
    int c  = t % NC;
    int b  = t / NC;
    int p0 = ph*256 + threadIdx.x*4;         // first of 4 states
    int cbi = 2*p0;
    size_t base = ((size_t)(b*Lz + c*CL))*1024;
    size_t ci = ((size_t)(b*NC + c))*Pz + p0;
    float Ar[4], Ai[4], fr[4], fi[4], xr[4], xi[4];
    f32x4 sr4 = *(const f32x4*)&SinRe[ci];
    f32x4 si4 = *(const f32x4*)&SinIm[ci];
    #pragma unroll
    for (int j=0;j<4;++j){
        Ar[j]=prm[p0+j]; Ai[j]=prm[Pz+p0+j];
        fr[j]=prm[2*Pz+p0+j]; fi[j]=prm[3*Pz+p0+j];
        xr[j]=sr4[j]; xi[j]=si4[j];
    }
    for (int ll=0; ll<CL; ++ll){
        short8v v8 = *(const short8v*)&g[base + cbi];
        short8v o8;
        #pragma unroll
        for (int j=0;j<4;++j){
            float gr = b2f((u16)v8[2*j]), gi = b2f((u16)v8[2*j+1]);
            float br = fr[j]*gr - fi[j]*gi;
            float bi = fr[j]*gi + fi[j]*gr;
            float nr = Ar[j]*xr[j] - Ai[j]*xi[j] + br;
            float ni = Ar[j]*xi[j] + Ai[j]*xr[j] + bi;
            xr[j]=nr; xi[j]=ni;
            o8[2*j]   = (short)f2b(nr);
            o8[2*j+1] = (short)f2b(ni);
        }
        *(short8v*)&g[base + cbi] = o8;
        base += 1024;
    }
}

extern "C" void kernel_launch(void* const* d_in, const int* in_sizes, int n_in,
                              void* d_out, int out_size, void* d_ws, size_t ws_size,
                              hipStream_t stream) {
    const float* x        = (const float*)d_in[0];
    const float* ln1_w    = (const float*)d_in[1];
    const float* ln1_b    = (const float*)d_in[2];
    const float* Lre      = (const float*)d_in[3];
    const float* Lim      = (const float*)d_in[4];
    const float* B_re     = (const float*)d_in[5];
    const float* B_im     = (const float*)d_in[6];
    const float* C_re     = (const float*)d_in[7];
    const float* C_im     = (const float*)d_in[8];
    const float* Dv       = (const float*)d_in[9];
    const float* log_step = (const float*)d_in[10];
    const float* ln2_w    = (const float*)d_in[11];
    const float* ln2_b    = (const float*)d_in[12];
    const float* W_enc    = (const float*)d_in[13];
    const float* W_dec    = (const float*)d_in[14];
    float* out = (float*)d_out;

    const size_t NH = (size_t)Nz*Hz;   // 8388608
    char* W = (char*)d_ws;
    u16*   fxb  = (u16*)  (W);                    // [N,512] bf16: fx, later ff
    u16*   g    = (u16*)  (W + NH*2);             // [N,1024] bf16 interleaved: g -> xs
    u16*   hb   = (u16*)  (W + NH*6);             // [N,512] bf16: h
    u16*   fx2b = (u16*)  (W + NH*8);             // [N,512] bf16: fx2
    float* ERe  = (float*)(W + NH*10);
    float* EIm  = ERe + CS;
    float* SinRe= EIm + CS;
    float* SinIm= SinRe + CS;
    float* prm  = SinIm + CS;                     // 6*Pz f32
    u16*   Bcat = (u16*)(prm + 6*Pz);             // [1024,512] interleaved rows
    u16*   Ccat = Bcat + 1024*512;                // [512,1024] interleaved cols
    u16*   Wenc = Ccat + 512*1024;                // [1024,512]
    u16*   Wdec = Wenc + 1024*512;                // [512,512]

    // weight converts + SSM setup in one launch
    cvt_all<<<dim3(6*1024 + 2), dim3(256), 0, stream>>>(
        B_re, B_im, C_re, C_im, W_enc, W_dec, Lre, Lim, log_step,
        Bcat, Ccat, Wenc, Wdec, prm);

    // LN1: x -> fxb (bf16)
    ln_kernel<float><<<dim3(Nz/4), dim3(256), 0, stream>>>(x, ln1_w, ln1_b, fxb);

    // GEMM1 + fused scan-phase1: g (interleaved) + E    grid 64x8 = 512 blocks
    gemmv<512,ESCAN><<<dim3(Nz/256, 1024/128), dim3(512), 0, stream>>>(
        fxb, Bcat, 1024, g, nullptr, nullptr, nullptr, nullptr, prm, ERe, EIm);

    // scan combine + phase2 (in place over g)
    scan_combine<<<dim3((Bz*Pz)/64), dim3(64), 0, stream>>>(ERe, EIm, prm, SinRe, SinIm);
    scan_phase2<<<dim3(Bz*NC*2), dim3(64), 0, stream>>>(g, prm, SinRe, SinIm);

    // GEMM2 (Y): h = gelu(2*(xs@Ccat^T) + D*fx) + fx -> hb   grid 64x4 = 256
    gemmv<1024,EY><<<dim3(Nz/256, 512/128), dim3(512), 0, stream>>>(
        g, Ccat, 512, hb, fxb, Dv, nullptr, nullptr, nullptr, nullptr, nullptr);

    // LN2: hb -> fx2b (bf16)
    ln_kernel<u16><<<dim3(Nz/4), dim3(256), 0, stream>>>(hb, ln2_w, ln2_b, fx2b);

    // GEMM3 + fused GEGLU, 2-panel persistent: ff -> fxb   grid 32x8 = 256
    gemmv<512,EGLU><<<dim3(Nz/512, 1024/128), dim3(512), 0, stream>>>(
        fx2b, Wenc, 1024, fxb, nullptr, nullptr, nullptr, nullptr, nullptr, nullptr, nullptr);

    // GEMM4: out = ff @ Wdec^T + fx2   grid 64x4 = 256
    gemmv<512,ERES><<<dim3(Nz/256, 512/128), dim3(512), 0, stream>>>(
        fxb, Wdec, 512, nullptr, nullptr, nullptr, fx2b, out, nullptr, nullptr, nullptr);
}

// Round 17
// 163.692 us; speedup vs baseline: 1.9724x; 1.0185x over previous
//
#include <hip/hip_runtime.h>
#include <math.h>

// (B,L,H,P) = (4,4096,512,512)
#define Bz 4
#define Lz 4096
#define Hz 512
#define Pz 512
#define Nz (Bz*Lz)          // 16384 rows
#define CL 32               // scan chunk length
#define NC (Lz/CL)          // 128 chunks
#define CS (Bz*NC*Pz)       // 262144 carry slots
#define EPSf 1e-5f

typedef unsigned short u16;
typedef unsigned int   u32;
typedef __attribute__((ext_vector_type(8))) short bf16x8;
typedef __attribute__((ext_vector_type(8))) short short8v;
typedef __attribute__((ext_vector_type(4))) float f32x4;

__device__ __forceinline__ float gelu_exact(float x){
    return 0.5f * x * (1.0f + erff(x * 0.70710678118654752f));
}
__device__ __forceinline__ u16 f2b(float f){
    union { float f; u32 u; } v; v.f = f;
    u32 u = v.u;
    u32 r = (u + 0x7FFFu + ((u >> 16) & 1u)) >> 16;   // RTNE
    return (u16)r;
}
__device__ __forceinline__ float b2f(u16 h){
    union { u32 u; float f; } v; v.u = ((u32)h) << 16; return v.f;
}

__device__ __forceinline__ void gload_lds16(const u16* g, u16* l){
    __builtin_amdgcn_global_load_lds(
        (const __attribute__((address_space(1))) void*)g,
        (__attribute__((address_space(3))) void*)l, 16, 0, 0);
}

// vectorized 8-element row loads (G13)
__device__ __forceinline__ void load8(const float* p, float* v){
    f32x4 a = *(const f32x4*)p, c = *(const f32x4*)(p+4);
    #pragma unroll
    for (int j=0;j<4;++j){ v[j]=a[j]; v[4+j]=c[j]; }
}
__device__ __forceinline__ void load8(const u16* p, float* v){
    short8v s = *(const short8v*)p;
    #pragma unroll
    for (int j=0;j<8;++j) v[j] = b2f((u16)s[j]);
}

// ---------------- prep: LN1 + weight converts + SSM setup (ONE launch) ------
// Blocks [0, Nz/4): LN1 rows (wave-per-row, vectorized).
// Blocks [Nz/4, Nz/4+6*1024): weight converts (interleaved complex layouts).
// Last 2 blocks: per-state SSM params. All parts independent -> co-scheduled
// across CUs instead of serialized on the stream (saves ~8us of serial prep).
#define LN1B (Nz/4)
__global__ __launch_bounds__(256) void prep_kernel(
        const float* __restrict__ x,
        const float* __restrict__ ln1_w, const float* __restrict__ ln1_b,
        const float* __restrict__ B_re,  const float* __restrict__ B_im,
        const float* __restrict__ C_re,  const float* __restrict__ C_im,
        const float* __restrict__ W_enc, const float* __restrict__ W_dec,
        const float* __restrict__ Lre,   const float* __restrict__ Lim,
        const float* __restrict__ log_step,
        u16* __restrict__ fxb,
        u16* __restrict__ Bcat, u16* __restrict__ Ccat,
        u16* __restrict__ Wenc, u16* __restrict__ Wdec,
        float* __restrict__ prm){
    const int Q = 512*512;
    int blk = blockIdx.x;
    if (blk < LN1B){   // ---- LN1 ----
        int row = blk*4 + (threadIdx.x >> 6);
        int l = threadIdx.x & 63;
        float v[8];
        load8(x + (size_t)row*Hz + l*8, v);
        float s = 0.f, q = 0.f;
        #pragma unroll
        for (int j=0;j<8;++j){ s += v[j]; q += v[j]*v[j]; }
        #pragma unroll
        for (int o=32;o;o>>=1){ s += __shfl_xor(s,o); q += __shfl_xor(q,o); }
        float mu = s * (1.0f/512.0f);
        float rs = rsqrtf(q * (1.0f/512.0f) - mu*mu + EPSf);
        short8v o8;
        #pragma unroll
        for (int j=0;j<8;++j){
            int m = l*8 + j;
            o8[j] = (short)f2b((v[j]-mu)*rs*ln1_w[m] + ln1_b[m]);
        }
        *(short8v*)&fxb[(size_t)row*Hz + l*8] = o8;
        return;
    }
    blk -= LN1B;
    if (blk >= 6*1024){   // ---- SSM setup ----
        int p = (blk - 6*1024)*256 + threadIdx.x;
        if (p >= Pz) return;
        float lr = Lre[p], li = Lim[p];
        float dt = expf(log_step[p]);
        float ar = lr*dt, ai = li*dt;
        float e = expf(ar);
        float Abr = e*cosf(ai), Abi = e*sinf(ai);   // Lambda_bar
        prm[p]        = Abr;
        prm[Pz + p]   = Abi;
        float nr = Abr - 1.0f, ni = Abi;
        float d2 = lr*lr + li*li;
        prm[2*Pz + p] = (nr*lr + ni*li)/d2;   // fRe
        prm[3*Pz + p] = (ni*lr - nr*li)/d2;   // fIm
        float arC = ar*(float)CL, aiC = ai*(float)CL;
        float eC = expf(arC);
        prm[4*Pz + p] = eC*cosf(aiC);         // ApowRe = A^CL
        prm[5*Pz + p] = eC*sinf(aiC);         // ApowIm
        return;
    }
    // ---- weight converts ----
    int i = blk*256 + threadIdx.x;
    if (i < Q){ int p=i>>9, h=i&511; Bcat[(size_t)(2*p)*512 + h]   = f2b(B_re[i]); return; }
    i -= Q;
    if (i < Q){ int p=i>>9, h=i&511; Bcat[(size_t)(2*p+1)*512 + h] = f2b(B_im[i]); return; }
    i -= Q;
    if (i < Q){
        int h = i >> 9, p = i & 511;
        Ccat[(size_t)h*1024 + 2*p]     = f2b(C_re[i]);
        Ccat[(size_t)h*1024 + 2*p + 1] = f2b(-C_im[i]);
        return;
    }
    i -= Q;
    if (i < 2*Q){ Wenc[i] = f2b(W_enc[i]); return; }
    i -= 2*Q;
    Wdec[i] = f2b(W_dec[i]);
}

// ---------------- LayerNorm (LN2): wave-per-row, vectorized ----------------
template<typename T>
__global__ __launch_bounds__(256) void ln_kernel(const T* __restrict__ in,
                                                 const float* __restrict__ w,
                                                 const float* __restrict__ b,
                                                 u16* __restrict__ ob){
    int row = blockIdx.x*4 + (threadIdx.x >> 6);
    int l = threadIdx.x & 63;
    float v[8];
    load8(in + (size_t)row*Hz + l*8, v);
    float s = 0.f, q = 0.f;
    #pragma unroll
    for (int j=0;j<8;++j){ s += v[j]; q += v[j]*v[j]; }
    #pragma unroll
    for (int o=32;o;o>>=1){ s += __shfl_xor(s,o); q += __shfl_xor(q,o); }
    float mu = s * (1.0f/512.0f);
    float rs = rsqrtf(q * (1.0f/512.0f) - mu*mu + EPSf);
    short8v o8;
    #pragma unroll
    for (int j=0;j<8;++j){
        int m = l*8 + j;
        o8[j] = (short)f2b((v[j]-mu)*rs*w[m] + b[m]);
    }
    *(short8v*)&ob[(size_t)row*Hz + l*8] = o8;
}

// ============ Counted-vmcnt triple-buffer 256x128 MFMA GEMM ============
// C[N,M] = A[N,K] @ Bw[M,K]^T. BM=256, BN=128, BK=64, 512 threads (8 waves,
// 4M x 2N; per-wave 64x64 -> acc[4][4], 32 MFMA + 16 ds_read_b128 per K-tile).
// LDS: 3 buffers x (A 32KB + B 16KB) = 144KB -> 1 block/CU, 2 waves/SIMD.
// Per K-tile: vmcnt(6) -> s_barrier -> stage tile T+2 -> ds_read + 32 MFMA.
// vmcnt NEVER drains to 0 mid-loop (T4). [R14-proven: broke the ~50us plateau]
// EGLU runs TWO 256-row panels per block in one seamless 16-tile pipeline.
#define EY    1
#define ERES  2
#define EGLU  3
#define ESCAN 4

#define ATW (256*64)
#define BTW (128*64)
#define TBW (ATW+BTW)

// A-tile 256x64 (32KB): 4 gload_lds/thread. Verified 0-conflict swizzle pair.
__device__ __forceinline__ void stageA256v(const u16* __restrict__ src, int ld,
                                           int row0, int kt, u16* lds){
    int lane = threadIdx.x & 63, w = threadIdx.x >> 6;
    #pragma unroll
    for (int q=0;q<4;++q){
        int c = w + q*8;                               // 1KB chunk, 0..31 (8 rows)
        int r = c*8 + (lane >> 3);                     // row 0..255
        int colE = 8*((lane & 7) ^ ((lane >> 3) & 7));
        gload_lds16(src + (size_t)(row0 + r)*ld + kt + colE, lds + c*512);
    }
}
// B-tile 128x64 (16KB): 2 gload_lds/thread
__device__ __forceinline__ void stageB128v(const u16* __restrict__ src, int ld,
                                           int row0, int kt, u16* lds){
    int lane = threadIdx.x & 63, w = threadIdx.x >> 6;
    #pragma unroll
    for (int q=0;q<2;++q){
        int c = w + q*8;                               // 0..15
        int r = c*8 + (lane >> 3);                     // row 0..127
        int colE = 8*((lane & 7) ^ ((lane >> 3) & 7));
        gload_lds16(src + (size_t)(row0 + r)*ld + kt + colE, lds + c*512);
    }
}
// GEGLU virtual-B: 16-row frags alternate a-rows / g-rows of Wenc (K=512)
__device__ __forceinline__ void stageBglu(const u16* __restrict__ Wenc, int fb,
                                          int kt, u16* lds){
    int lane = threadIdx.x & 63, w = threadIdx.x >> 6;
    #pragma unroll
    for (int q=0;q<2;++q){
        int c = w + q*8;
        int v = c*8 + (lane >> 3);                     // virtual row 0..127
        int vf = v >> 4, r = v & 15;
        int grow = ((vf & 1) ? 512 : 0) + fb + (vf >> 1)*16 + r;
        int colE = 8*((lane & 7) ^ ((lane >> 3) & 7));
        gload_lds16(Wenc + (size_t)grow*512 + kt + colE, lds + c*512);
    }
}

template<int K, int EPI>
__global__ __launch_bounds__(512)
void gemmv(const u16* __restrict__ A, const u16* __restrict__ Bw, int M,
           u16* __restrict__ outB,
           const u16* __restrict__ fxB,        // EY
           const float* __restrict__ Dv,       // EY
           const u16* __restrict__ resB,       // ERES
           float* __restrict__ outF,           // ERES
           const float* __restrict__ prm,      // ESCAN
           float* __restrict__ ERe,            // ESCAN
           float* __restrict__ EIm)            // ESCAN
{
    constexpr int NT = K/64;
    constexpr int NP = (EPI==EGLU) ? 2 : 1;     // panels per block
    constexpr int TT = NT*NP;                    // total tiles in pipeline
    __shared__ u16 LDS[3*TBW];   // 144KB

    int nx = gridDim.x, ny = gridDim.y;
    int nwg = nx*ny;
    int lid = blockIdx.x + blockIdx.y*nx;
    int cpx = nwg >> 3;
    int gdx = (lid & 7)*cpx + (lid >> 3);
    int n0 = (gdx / ny) * 256 * NP;
    int mb = gdx % ny;
    int m0 = mb * 128;          // output-col block (virtual for EGLU)
    int fb = mb * 64;           // EGLU ff-col base

    int l = threadIdx.x & 63;
    int w = threadIdx.x >> 6;
    int wm = w >> 1, wn = w & 1;
    int rb = wm*64, cb = wn*64;
    int lrow  = l & 15;
    int lcol0 = ((l >> 4)*8) ^ ((l & 7) << 3);
    int lcol1 = lcol0 ^ 32;
    int er = (l >> 4) * 4;
    int ec = l & 15;

    f32x4 acc[4][4];
    #pragma unroll
    for (int i=0;i<4;++i)
        #pragma unroll
        for (int j=0;j<4;++j) acc[i][j] = (f32x4)(0.f);

    // prologue: stage tiles 0 and 1 (12 loads/thread outstanding)
    stageA256v(A, K, n0, 0, &LDS[0]);
    if (EPI==EGLU) stageBglu(Bw, fb, 0, &LDS[ATW]); else stageB128v(Bw, K, m0, 0, &LDS[ATW]);
    stageA256v(A, K, n0, 64, &LDS[TBW]);
    if (EPI==EGLU) stageBglu(Bw, fb, 64, &LDS[TBW+ATW]); else stageB128v(Bw, K, m0, 64, &LDS[TBW+ATW]);

    for (int T=0; T<TT; ++T){
        if (T == TT-1){ asm volatile("s_waitcnt vmcnt(0)" ::: "memory"); }
        else          { asm volatile("s_waitcnt vmcnt(6)" ::: "memory"); }
        __builtin_amdgcn_s_barrier();
        if (T+2 < TT){
            u16* buf = &LDS[((T+2)%3)*TBW];
            int t2 = T+2;
            int ktn = (t2 % NT)*64;
            int rowA = n0 + (t2/NT)*256;
            stageA256v(A, K, rowA, ktn, buf);
            if (EPI==EGLU) stageBglu(Bw, fb, ktn, buf+ATW); else stageB128v(Bw, K, m0, ktn, buf+ATW);
        }
        const u16* Ab = &LDS[(T%3)*TBW];
        const u16* Bb = Ab + ATW;
        bf16x8 a0[4], a1[4], b0[4], b1[4];
        #pragma unroll
        for (int f=0; f<4; ++f){
            a0[f] = *(const bf16x8*)&Ab[(rb + f*16 + lrow)*64 + lcol0];
            a1[f] = *(const bf16x8*)&Ab[(rb + f*16 + lrow)*64 + lcol1];
        }
        #pragma unroll
        for (int g=0; g<4; ++g){
            b0[g] = *(const bf16x8*)&Bb[(cb + g*16 + lrow)*64 + lcol0];
            b1[g] = *(const bf16x8*)&Bb[(cb + g*16 + lrow)*64 + lcol1];
        }
        __builtin_amdgcn_s_setprio(1);
        #pragma unroll
        for (int f=0; f<4; ++f)
            #pragma unroll
            for (int g=0; g<4; ++g){
                acc[f][g] = __builtin_amdgcn_mfma_f32_16x16x32_bf16(a0[f], b0[g], acc[f][g], 0,0,0);
                acc[f][g] = __builtin_amdgcn_mfma_f32_16x16x32_bf16(a1[f], b1[g], acc[f][g], 0,0,0);
            }
        __builtin_amdgcn_s_setprio(0);
        // EGLU panel-0 epilogue mid-pipeline (no LDS use; pipeline keeps flowing)
        if (EPI==EGLU && NP==2 && T == NT-1){
            #pragma unroll
            for (int fm=0; fm<4; ++fm)
                #pragma unroll
                for (int pr=0; pr<2; ++pr)
                    #pragma unroll
                    for (int q=0; q<4; ++q){
                        int n = n0 + rb + fm*16 + er + q;
                        int col = fb + (wn*2 + pr)*16 + ec;
                        float ffv = acc[fm][2*pr][q] * gelu_exact(acc[fm][2*pr+1][q]);
                        outB[(size_t)n*Hz + col] = f2b(ffv);
                    }
            #pragma unroll
            for (int i=0;i<4;++i)
                #pragma unroll
                for (int j=0;j<4;++j) acc[i][j] = (f32x4)(0.f);
        }
    }

    if (EPI == ESCAN){
        u16* gt = (u16*)LDS;   // alias staging (dead); [256][128] u16 = 64KB
        __syncthreads();
        #pragma unroll
        for (int fm=0; fm<4; ++fm)
            #pragma unroll
            for (int g=0; g<4; ++g)
                #pragma unroll
                for (int q=0; q<4; ++q){
                    int rr = rb + fm*16 + er + q;
                    int cc = cb + g*16 + ec;
                    u16 hv = f2b(acc[fm][g][q]);
                    outB[(size_t)(n0 + rr)*M + (m0 + cc)] = hv;
                    gt[rr*128 + cc] = hv;
                }
        __syncthreads();
        // fused scan phase1 @ CL=32: ALL 512 threads (p = tid&63, h = tid>>6)
        int tid = threadIdx.x;
        int p = tid & 63, h = tid >> 6;          // h 0..7 (8 chunks of 32 rows)
        int P = (m0 >> 1) + p;
        int b = n0 >> 12;
        int c = ((n0 & 4095) >> 5) + h;
        float Ar = prm[P], Ai = prm[Pz+P];
        float fre = prm[2*Pz+P], fim = prm[3*Pz+P];
        float xr = 0.f, xi = 0.f;
        int base = h*32*128 + 2*p;
        #pragma unroll 8
        for (int r = 0; r < 32; ++r){
            u32 v = *(const u32*)&gt[base + r*128];
            float gr = b2f((u16)(v & 0xffff));
            float gi = b2f((u16)(v >> 16));
            float br = fre*gr - fim*gi;
            float bi = fre*gi + fim*gr;
            float nr2 = Ar*xr - Ai*xi + br;
            float ni2 = Ar*xi + Ai*xr + bi;
            xr = nr2; xi = ni2;
        }
        size_t ci = ((size_t)(b*NC + c))*Pz + P;
        ERe[ci] = xr; EIm[ci] = xi;
    } else if (EPI == EGLU){
        int nb = n0 + (NP-1)*256;   // last panel
        #pragma unroll
        for (int fm=0; fm<4; ++fm)
            #pragma unroll
            for (int pr=0; pr<2; ++pr)
                #pragma unroll
                for (int q=0; q<4; ++q){
                    int n = nb + rb + fm*16 + er + q;
                    int col = fb + (wn*2 + pr)*16 + ec;
                    float ffv = acc[fm][2*pr][q] * gelu_exact(acc[fm][2*pr+1][q]);
                    outB[(size_t)n*Hz + col] = f2b(ffv);
                }
    } else {
        #pragma unroll
        for (int fm=0; fm<4; ++fm)
            #pragma unroll
            for (int g=0; g<4; ++g)
                #pragma unroll
                for (int q=0; q<4; ++q){
                    int n = n0 + rb + fm*16 + er + q;
                    int m = m0 + cb + g*16 + ec;
                    float v = acc[fm][g][q];
                    if (EPI == EY){
                        size_t idx = (size_t)n*Hz + m;
                        float fxv = b2f(fxB[idx]);
                        float y = 2.0f*v + Dv[m]*fxv;
                        outB[idx] = f2b(gelu_exact(y) + fxv);
                    } else {  // ERES
                        size_t idx = (size_t)n*Hz + m;
                        outF[idx] = v + b2f(resB[idx]);
                    }
                }
    }
}

// ---------------- scan combine (NC=128 chunks; 32 blocks x 64 thr) ----------
__global__ __launch_bounds__(64) void scan_combine(const float* __restrict__ ERe,
                                                   const float* __restrict__ EIm,
                                                   const float* __restrict__ prm,
                                                   float* __restrict__ SinRe,
                                                   float* __restrict__ SinIm){
    int gt = blockIdx.x*64 + threadIdx.x;   // over B*P
    int b = gt / Pz, p = gt % Pz;
    float Ar = prm[4*Pz+p], Ai = prm[5*Pz+p];
    float Sr = 0.f, Si = 0.f;
    for (int c = 0; c < NC; ++c) {
        size_t idx = ((size_t)(b*NC + c))*Pz + p;
        SinRe[idx] = Sr; SinIm[idx] = Si;
        float er = ERe[idx], ei = EIm[idx];
        float nr = Ar*Sr - Ai*Si + er;
        float ni = Ar*Si + Ai*Sr + ei;
        Sr = nr; Si = ni;
    }
}

// ---------------- scan phase2: interleaved, short8 (16B) per row ------------
// CL=32: grid Bz*NC*2 = 1024 blocks x 64 thr, 32-iter chains.
__global__ __launch_bounds__(64) void scan_phase2(u16* __restrict__ g,
                                                  const float* __restrict__ prm,
                                                  const float* __restrict__ SinRe,
                                                  const float* __restrict__ SinIm){
    int t = blockIdx.x;
    int ph = t & 1; t >>= 1;
    int c  = t % NC;
    int b  = t / NC;
    int p0 = ph*256 + threadIdx.x*4;         // first of 4 states
    int cbi = 2*p0;
    size_t base = ((size_t)(b*Lz + c*CL))*1024;
    size_t ci = ((size_t)(b*NC + c))*Pz + p0;
    float Ar[4], Ai[4], fr[4], fi[4], xr[4], xi[4];
    f32x4 sr4 = *(const f32x4*)&SinRe[ci];
    f32x4 si4 = *(const f32x4*)&SinIm[ci];
    #pragma unroll
    for (int j=0;j<4;++j){
        Ar[j]=prm[p0+j]; Ai[j]=prm[Pz+p0+j];
        fr[j]=prm[2*Pz+p0+j]; fi[j]=prm[3*Pz+p0+j];
        xr[j]=sr4[j]; xi[j]=si4[j];
    }
    for (int ll=0; ll<CL; ++ll){
        short8v v8 = *(const short8v*)&g[base + cbi];
        short8v o8;
        #pragma unroll
        for (int j=0;j<4;++j){
            float gr = b2f((u16)v8[2*j]), gi = b2f((u16)v8[2*j+1]);
            float br = fr[j]*gr - fi[j]*gi;
            float bi = fr[j]*gi + fi[j]*gr;
            float nr = Ar[j]*xr[j] - Ai[j]*xi[j] + br;
            float ni = Ar[j]*xi[j] + Ai[j]*xr[j] + bi;
            xr[j]=nr; xi[j]=ni;
            o8[2*j]   = (short)f2b(nr);
            o8[2*j+1] = (short)f2b(ni);
        }
        *(short8v*)&g[base + cbi] = o8;
        base += 1024;
    }
}

extern "C" void kernel_launch(void* const* d_in, const int* in_sizes, int n_in,
                              void* d_out, int out_size, void* d_ws, size_t ws_size,
                              hipStream_t stream) {
    const float* x        = (const float*)d_in[0];
    const float* ln1_w    = (const float*)d_in[1];
    const float* ln1_b    = (const float*)d_in[2];
    const float* Lre      = (const float*)d_in[3];
    const float* Lim      = (const float*)d_in[4];
    const float* B_re     = (const float*)d_in[5];
    const float* B_im     = (const float*)d_in[6];
    const float* C_re     = (const float*)d_in[7];
    const float* C_im     = (const float*)d_in[8];
    const float* Dv       = (const float*)d_in[9];
    const float* log_step = (const float*)d_in[10];
    const float* ln2_w    = (const float*)d_in[11];
    const float* ln2_b    = (const float*)d_in[12];
    const float* W_enc    = (const float*)d_in[13];
    const float* W_dec    = (const float*)d_in[14];
    float* out = (float*)d_out;

    const size_t NH = (size_t)Nz*Hz;   // 8388608
    char* W = (char*)d_ws;
    u16*   fxb  = (u16*)  (W);                    // [N,512] bf16: fx, later ff
    u16*   g    = (u16*)  (W + NH*2);             // [N,1024] bf16 interleaved: g -> xs
    u16*   hb   = (u16*)  (W + NH*6);             // [N,512] bf16: h
    u16*   fx2b = (u16*)  (W + NH*8);             // [N,512] bf16: fx2
    float* ERe  = (float*)(W + NH*10);
    float* EIm  = ERe + CS;
    float* SinRe= EIm + CS;
    float* SinIm= SinRe + CS;
    float* prm  = SinIm + CS;                     // 6*Pz f32
    u16*   Bcat = (u16*)(prm + 6*Pz);             // [1024,512] interleaved rows
    u16*   Ccat = Bcat + 1024*512;                // [512,1024] interleaved cols
    u16*   Wenc = Ccat + 512*1024;                // [1024,512]
    u16*   Wdec = Wenc + 1024*512;                // [512,512]

    // LN1 + weight converts + SSM setup, one co-scheduled launch
    prep_kernel<<<dim3(LN1B + 6*1024 + 2), dim3(256), 0, stream>>>(
        x, ln1_w, ln1_b, B_re, B_im, C_re, C_im, W_enc, W_dec,
        Lre, Lim, log_step, fxb, Bcat, Ccat, Wenc, Wdec, prm);

    // GEMM1 + fused scan-phase1: g (interleaved) + E    grid 64x8 = 512 blocks
    gemmv<512,ESCAN><<<dim3(Nz/256, 1024/128), dim3(512), 0, stream>>>(
        fxb, Bcat, 1024, g, nullptr, nullptr, nullptr, nullptr, prm, ERe, EIm);

    // scan combine + phase2 (in place over g)
    scan_combine<<<dim3((Bz*Pz)/64), dim3(64), 0, stream>>>(ERe, EIm, prm, SinRe, SinIm);
    scan_phase2<<<dim3(Bz*NC*2), dim3(64), 0, stream>>>(g, prm, SinRe, SinIm);

    // GEMM2 (Y): h = gelu(2*(xs@Ccat^T) + D*fx) + fx -> hb   grid 64x4 = 256
    gemmv<1024,EY><<<dim3(Nz/256, 512/128), dim3(512), 0, stream>>>(
        g, Ccat, 512, hb, fxb, Dv, nullptr, nullptr, nullptr, nullptr, nullptr);

    // LN2: hb -> fx2b (bf16)
    ln_kernel<u16><<<dim3(Nz/4), dim3(256), 0, stream>>>(hb, ln2_w, ln2_b, fx2b);

    // GEMM3 + fused GEGLU, 2-panel persistent: ff -> fxb   grid 32x8 = 256
    gemmv<512,EGLU><<<dim3(Nz/512, 1024/128), dim3(512), 0, stream>>>(
        fx2b, Wenc, 1024, fxb, nullptr, nullptr, nullptr, nullptr, nullptr, nullptr, nullptr);

    // GEMM4: out = ff @ Wdec^T + fx2   grid 64x4 = 256
    gemmv<512,ERES><<<dim3(Nz/256, 512/128), dim3(512), 0, stream>>>(
        fxb, Wdec, 512, nullptr, nullptr, nullptr, fx2b, out, nullptr, nullptr, nullptr);
}

// Round 18
// 161.431 us; speedup vs baseline: 2.0000x; 1.0140x over previous
//
#include <hip/hip_runtime.h>
#include <math.h>

// (B,L,H,P) = (4,4096,512,512)
#define Bz 4
#define Lz 4096
#define Hz 512
#define Pz 512
#define Nz (Bz*Lz)          // 16384 rows
#define CL 32               // scan chunk length
#define NC (Lz/CL)          // 128 chunks
#define CS (Bz*NC*Pz)       // 262144 carry slots
#define EPSf 1e-5f

typedef unsigned short u16;
typedef unsigned int   u32;
typedef __attribute__((ext_vector_type(8))) short bf16x8;
typedef __attribute__((ext_vector_type(8))) short short8v;
typedef __attribute__((ext_vector_type(4))) float f32x4;

__device__ __forceinline__ float gelu_exact(float x){
    return 0.5f * x * (1.0f + erff(x * 0.70710678118654752f));
}
__device__ __forceinline__ u16 f2b(float f){
    union { float f; u32 u; } v; v.f = f;
    u32 u = v.u;
    u32 r = (u + 0x7FFFu + ((u >> 16) & 1u)) >> 16;   // RTNE
    return (u16)r;
}
__device__ __forceinline__ float b2f(u16 h){
    union { u32 u; float f; } v; v.u = ((u32)h) << 16; return v.f;
}

__device__ __forceinline__ void gload_lds16(const u16* g, u16* l){
    __builtin_amdgcn_global_load_lds(
        (const __attribute__((address_space(1))) void*)g,
        (__attribute__((address_space(3))) void*)l, 16, 0, 0);
}

// vectorized 8-element row loads (G13)
__device__ __forceinline__ void load8(const float* p, float* v){
    f32x4 a = *(const f32x4*)p, c = *(const f32x4*)(p+4);
    #pragma unroll
    for (int j=0;j<4;++j){ v[j]=a[j]; v[4+j]=c[j]; }
}
__device__ __forceinline__ void load8(const u16* p, float* v){
    short8v s = *(const short8v*)p;
    #pragma unroll
    for (int j=0;j<8;++j) v[j] = b2f((u16)s[j]);
}

// ---------------- prep: LN1 + weight converts + SSM setup (ONE launch) ------
#define LN1B (Nz/4)
__global__ __launch_bounds__(256) void prep_kernel(
        const float* __restrict__ x,
        const float* __restrict__ ln1_w, const float* __restrict__ ln1_b,
        const float* __restrict__ B_re,  const float* __restrict__ B_im,
        const float* __restrict__ C_re,  const float* __restrict__ C_im,
        const float* __restrict__ W_enc, const float* __restrict__ W_dec,
        const float* __restrict__ Lre,   const float* __restrict__ Lim,
        const float* __restrict__ log_step,
        u16* __restrict__ fxb,
        u16* __restrict__ Bcat, u16* __restrict__ Ccat,
        u16* __restrict__ Wenc, u16* __restrict__ Wdec,
        float* __restrict__ prm){
    const int Q = 512*512;
    int blk = blockIdx.x;
    if (blk < LN1B){   // ---- LN1 ----
        int row = blk*4 + (threadIdx.x >> 6);
        int l = threadIdx.x & 63;
        float v[8];
        load8(x + (size_t)row*Hz + l*8, v);
        float s = 0.f, q = 0.f;
        #pragma unroll
        for (int j=0;j<8;++j){ s += v[j]; q += v[j]*v[j]; }
        #pragma unroll
        for (int o=32;o;o>>=1){ s += __shfl_xor(s,o); q += __shfl_xor(q,o); }
        float mu = s * (1.0f/512.0f);
        float rs = rsqrtf(q * (1.0f/512.0f) - mu*mu + EPSf);
        short8v o8;
        #pragma unroll
        for (int j=0;j<8;++j){
            int m = l*8 + j;
            o8[j] = (short)f2b((v[j]-mu)*rs*ln1_w[m] + ln1_b[m]);
        }
        *(short8v*)&fxb[(size_t)row*Hz + l*8] = o8;
        return;
    }
    blk -= LN1B;
    if (blk >= 6*1024){   // ---- SSM setup ----
        int p = (blk - 6*1024)*256 + threadIdx.x;
        if (p >= Pz) return;
        float lr = Lre[p], li = Lim[p];
        float dt = expf(log_step[p]);
        float ar = lr*dt, ai = li*dt;
        float e = expf(ar);
        float Abr = e*cosf(ai), Abi = e*sinf(ai);   // Lambda_bar
        prm[p]        = Abr;
        prm[Pz + p]   = Abi;
        float nr = Abr - 1.0f, ni = Abi;
        float d2 = lr*lr + li*li;
        prm[2*Pz + p] = (nr*lr + ni*li)/d2;   // fRe
        prm[3*Pz + p] = (ni*lr - nr*li)/d2;   // fIm
        float arC = ar*(float)CL, aiC = ai*(float)CL;
        float eC = expf(arC);
        prm[4*Pz + p] = eC*cosf(aiC);         // ApowRe = A^CL
        prm[5*Pz + p] = eC*sinf(aiC);         // ApowIm
        return;
    }
    // ---- weight converts ----
    int i = blk*256 + threadIdx.x;
    if (i < Q){ int p=i>>9, h=i&511; Bcat[(size_t)(2*p)*512 + h]   = f2b(B_re[i]); return; }
    i -= Q;
    if (i < Q){ int p=i>>9, h=i&511; Bcat[(size_t)(2*p+1)*512 + h] = f2b(B_im[i]); return; }
    i -= Q;
    if (i < Q){
        int h = i >> 9, p = i & 511;
        Ccat[(size_t)h*1024 + 2*p]     = f2b(C_re[i]);
        Ccat[(size_t)h*1024 + 2*p + 1] = f2b(-C_im[i]);
        return;
    }
    i -= Q;
    if (i < 2*Q){ Wenc[i] = f2b(W_enc[i]); return; }
    i -= 2*Q;
    Wdec[i] = f2b(W_dec[i]);
}

// ---------------- LayerNorm (LN2): wave-per-row, vectorized ----------------
template<typename T>
__global__ __launch_bounds__(256) void ln_kernel(const T* __restrict__ in,
                                                 const float* __restrict__ w,
                                                 const float* __restrict__ b,
                                                 u16* __restrict__ ob){
    int row = blockIdx.x*4 + (threadIdx.x >> 6);
    int l = threadIdx.x & 63;
    float v[8];
    load8(in + (size_t)row*Hz + l*8, v);
    float s = 0.f, q = 0.f;
    #pragma unroll
    for (int j=0;j<8;++j){ s += v[j]; q += v[j]*v[j]; }
    #pragma unroll
    for (int o=32;o;o>>=1){ s += __shfl_xor(s,o); q += __shfl_xor(q,o); }
    float mu = s * (1.0f/512.0f);
    float rs = rsqrtf(q * (1.0f/512.0f) - mu*mu + EPSf);
    short8v o8;
    #pragma unroll
    for (int j=0;j<8;++j){
        int m = l*8 + j;
        o8[j] = (short)f2b((v[j]-mu)*rs*w[m] + b[m]);
    }
    *(short8v*)&ob[(size_t)row*Hz + l*8] = o8;
}

// ============ Counted-vmcnt triple-buffer 256x128 MFMA GEMM ============
// [R14-proven schedule] BM=256, BN=128, BK=64, 8 waves; vmcnt(6) per tile,
// never 0 mid-loop; 3 LDS buffers (144KB). EGLU: 2 n-panels per block.
#define EY    1
#define ERES  2
#define EGLU  3

#define ATW (256*64)
#define BTW (128*64)
#define TBW (ATW+BTW)

__device__ __forceinline__ void stageA256v(const u16* __restrict__ src, int ld,
                                           int row0, int kt, u16* lds){
    int lane = threadIdx.x & 63, w = threadIdx.x >> 6;
    #pragma unroll
    for (int q=0;q<4;++q){
        int c = w + q*8;                               // 1KB chunk, 0..31 (8 rows)
        int r = c*8 + (lane >> 3);                     // row 0..255
        int colE = 8*((lane & 7) ^ ((lane >> 3) & 7));
        gload_lds16(src + (size_t)(row0 + r)*ld + kt + colE, lds + c*512);
    }
}
__device__ __forceinline__ void stageB128v(const u16* __restrict__ src, int ld,
                                           int row0, int kt, u16* lds){
    int lane = threadIdx.x & 63, w = threadIdx.x >> 6;
    #pragma unroll
    for (int q=0;q<2;++q){
        int c = w + q*8;                               // 0..15
        int r = c*8 + (lane >> 3);                     // row 0..127
        int colE = 8*((lane & 7) ^ ((lane >> 3) & 7));
        gload_lds16(src + (size_t)(row0 + r)*ld + kt + colE, lds + c*512);
    }
}
// GEGLU virtual-B: 16-row frags alternate a-rows / g-rows of Wenc (K=512)
__device__ __forceinline__ void stageBglu(const u16* __restrict__ Wenc, int fb,
                                          int kt, u16* lds){
    int lane = threadIdx.x & 63, w = threadIdx.x >> 6;
    #pragma unroll
    for (int q=0;q<2;++q){
        int c = w + q*8;
        int v = c*8 + (lane >> 3);                     // virtual row 0..127
        int vf = v >> 4, r = v & 15;
        int grow = ((vf & 1) ? 512 : 0) + fb + (vf >> 1)*16 + r;
        int colE = 8*((lane & 7) ^ ((lane >> 3) & 7));
        gload_lds16(Wenc + (size_t)grow*512 + kt + colE, lds + c*512);
    }
}

template<int K, int EPI>
__global__ __launch_bounds__(512)
void gemmv(const u16* __restrict__ A, const u16* __restrict__ Bw, int M,
           u16* __restrict__ outB,
           const u16* __restrict__ fxB,        // EY
           const float* __restrict__ Dv,       // EY
           const u16* __restrict__ resB,       // ERES
           float* __restrict__ outF)           // ERES
{
    constexpr int NT = K/64;
    constexpr int NP = (EPI==EGLU) ? 2 : 1;     // n-panels per block
    constexpr int TT = NT*NP;
    __shared__ u16 LDS[3*TBW];   // 144KB

    int nx = gridDim.x, ny = gridDim.y;
    int nwg = nx*ny;
    int lid = blockIdx.x + blockIdx.y*nx;
    int cpx = nwg >> 3;
    int gdx = (lid & 7)*cpx + (lid >> 3);
    int n0 = (gdx / ny) * 256 * NP;
    int mb = gdx % ny;
    int m0 = mb * 128;
    int fb = mb * 64;           // EGLU ff-col base

    int l = threadIdx.x & 63;
    int w = threadIdx.x >> 6;
    int wm = w >> 1, wn = w & 1;
    int rb = wm*64, cb = wn*64;
    int lrow  = l & 15;
    int lcol0 = ((l >> 4)*8) ^ ((l & 7) << 3);
    int lcol1 = lcol0 ^ 32;
    int er = (l >> 4) * 4;
    int ec = l & 15;

    f32x4 acc[4][4];
    #pragma unroll
    for (int i=0;i<4;++i)
        #pragma unroll
        for (int j=0;j<4;++j) acc[i][j] = (f32x4)(0.f);

    stageA256v(A, K, n0, 0, &LDS[0]);
    if (EPI==EGLU) stageBglu(Bw, fb, 0, &LDS[ATW]); else stageB128v(Bw, K, m0, 0, &LDS[ATW]);
    stageA256v(A, K, n0, 64, &LDS[TBW]);
    if (EPI==EGLU) stageBglu(Bw, fb, 64, &LDS[TBW+ATW]); else stageB128v(Bw, K, m0, 64, &LDS[TBW+ATW]);

    for (int T=0; T<TT; ++T){
        if (T == TT-1){ asm volatile("s_waitcnt vmcnt(0)" ::: "memory"); }
        else          { asm volatile("s_waitcnt vmcnt(6)" ::: "memory"); }
        __builtin_amdgcn_s_barrier();
        if (T+2 < TT){
            u16* buf = &LDS[((T+2)%3)*TBW];
            int t2 = T+2;
            int ktn = (t2 % NT)*64;
            int rowA = n0 + (t2/NT)*256;
            stageA256v(A, K, rowA, ktn, buf);
            if (EPI==EGLU) stageBglu(Bw, fb, ktn, buf+ATW); else stageB128v(Bw, K, m0, ktn, buf+ATW);
        }
        const u16* Ab = &LDS[(T%3)*TBW];
        const u16* Bb = Ab + ATW;
        bf16x8 a0[4], a1[4], b0[4], b1[4];
        #pragma unroll
        for (int f=0; f<4; ++f){
            a0[f] = *(const bf16x8*)&Ab[(rb + f*16 + lrow)*64 + lcol0];
            a1[f] = *(const bf16x8*)&Ab[(rb + f*16 + lrow)*64 + lcol1];
        }
        #pragma unroll
        for (int g=0; g<4; ++g){
            b0[g] = *(const bf16x8*)&Bb[(cb + g*16 + lrow)*64 + lcol0];
            b1[g] = *(const bf16x8*)&Bb[(cb + g*16 + lrow)*64 + lcol1];
        }
        __builtin_amdgcn_s_setprio(1);
        #pragma unroll
        for (int f=0; f<4; ++f)
            #pragma unroll
            for (int g=0; g<4; ++g){
                acc[f][g] = __builtin_amdgcn_mfma_f32_16x16x32_bf16(a0[f], b0[g], acc[f][g], 0,0,0);
                acc[f][g] = __builtin_amdgcn_mfma_f32_16x16x32_bf16(a1[f], b1[g], acc[f][g], 0,0,0);
            }
        __builtin_amdgcn_s_setprio(0);
        if (EPI==EGLU && NP==2 && T == NT-1){
            #pragma unroll
            for (int fm=0; fm<4; ++fm)
                #pragma unroll
                for (int pr=0; pr<2; ++pr)
                    #pragma unroll
                    for (int q=0; q<4; ++q){
                        int n = n0 + rb + fm*16 + er + q;
                        int col = fb + (wn*2 + pr)*16 + ec;
                        float ffv = acc[fm][2*pr][q] * gelu_exact(acc[fm][2*pr+1][q]);
                        outB[(size_t)n*Hz + col] = f2b(ffv);
                    }
            #pragma unroll
            for (int i=0;i<4;++i)
                #pragma unroll
                for (int j=0;j<4;++j) acc[i][j] = (f32x4)(0.f);
        }
    }

    if (EPI == EGLU){
        int nb = n0 + (NP-1)*256;
        #pragma unroll
        for (int fm=0; fm<4; ++fm)
            #pragma unroll
            for (int pr=0; pr<2; ++pr)
                #pragma unroll
                for (int q=0; q<4; ++q){
                    int n = nb + rb + fm*16 + er + q;
                    int col = fb + (wn*2 + pr)*16 + ec;
                    float ffv = acc[fm][2*pr][q] * gelu_exact(acc[fm][2*pr+1][q]);
                    outB[(size_t)n*Hz + col] = f2b(ffv);
                }
    } else {
        #pragma unroll
        for (int fm=0; fm<4; ++fm)
            #pragma unroll
            for (int g=0; g<4; ++g)
                #pragma unroll
                for (int q=0; q<4; ++q){
                    int n = n0 + rb + fm*16 + er + q;
                    int m = m0 + cb + g*16 + ec;
                    float v = acc[fm][g][q];
                    if (EPI == EY){
                        size_t idx = (size_t)n*Hz + m;
                        float fxv = b2f(fxB[idx]);
                        float y = 2.0f*v + Dv[m]*fxv;
                        outB[idx] = f2b(gelu_exact(y) + fxv);
                    } else {  // ERES
                        size_t idx = (size_t)n*Hz + m;
                        outF[idx] = v + b2f(resB[idx]);
                    }
                }
    }
}

// ============ GEMM1 + scan, 2-m-panel persistent (grid 256 = 1 round) ======
// Block: 256 rows x 256 g-cols (two 128-col panels sharing every A-tile).
// BK=32: per buffer A 16KB + B0 8KB + B1 8KB = 32KB; x3 = 96KB.
// Per tile: 4 loads/thread; vmcnt(4) -> barrier -> stage T+2 -> 32 MFMA/wave
// (16 per panel) — R14 cover, R14 WAR proof. 32-col swizzle pair (R9-verified,
// conflicts=0): stage colE=8*((lane&3)^((lane>>3)&3)), read lcol=8*((l>>4)^((l>>1)&3)).
#define ATW2 (256*32)
#define BTW2 (128*32)
#define TBW2 (ATW2 + 2*BTW2)   // 16384 u16 = 32KB

__device__ __forceinline__ void stageA256k32(const u16* __restrict__ src,
                                             int row0, int kt, u16* lds){
    int lane = threadIdx.x & 63, w = threadIdx.x >> 6;
    #pragma unroll
    for (int q=0;q<2;++q){
        int c = w + q*8;                               // 1KB chunk, 0..15 (16 rows)
        int r = c*16 + (lane >> 2);                    // row 0..255
        int colE = 8*((lane & 3) ^ ((lane >> 3) & 3));
        gload_lds16(src + (size_t)(row0 + r)*512 + kt + colE, lds + c*512);
    }
}
__device__ __forceinline__ void stageB128k32(const u16* __restrict__ src,
                                             int row0, int kt, u16* lds){
    int lane = threadIdx.x & 63, w = threadIdx.x >> 6;   // w 0..7 = chunk
    int r = w*16 + (lane >> 2);                          // row 0..127
    int colE = 8*((lane & 3) ^ ((lane >> 3) & 3));
    gload_lds16(src + (size_t)(row0 + r)*512 + kt + colE, lds + w*512);
}

__global__ __launch_bounds__(512)
void gemm1_scan2(const u16* __restrict__ A, const u16* __restrict__ Bw,
                 u16* __restrict__ outB,
                 const float* __restrict__ prm,
                 float* __restrict__ ERe, float* __restrict__ EIm)
{
    constexpr int NT = 16;   // K=512, BK=32
    __shared__ u16 LDS[3*TBW2];   // 96KB

    int nwg = gridDim.x;          // 256
    int lid = blockIdx.x;
    int cpx = nwg >> 3;
    int gdx = (lid & 7)*cpx + (lid >> 3);
    int n0 = (gdx >> 2) * 256;    // 64 n-blocks
    int mb = gdx & 3;             // 4 m-blocks of 256 g-cols
    int m0a = mb*256, m0b = mb*256 + 128;

    int l = threadIdx.x & 63;
    int w = threadIdx.x >> 6;
    int wm = w >> 1, wn = w & 1;
    int rb = wm*64, cb = wn*64;
    int lrow = l & 15;
    int lcol = 8*((l >> 4) ^ ((l >> 1) & 3));
    int er = (l >> 4) * 4;
    int ec = l & 15;

    f32x4 accA[4][4], accB[4][4];
    #pragma unroll
    for (int i=0;i<4;++i)
        #pragma unroll
        for (int j=0;j<4;++j){ accA[i][j]=(f32x4)(0.f); accB[i][j]=(f32x4)(0.f); }

    // prologue: tiles 0,1 (4 loads/thread each)
    stageA256k32(A, n0, 0, &LDS[0]);
    stageB128k32(Bw, m0a, 0, &LDS[ATW2]);
    stageB128k32(Bw, m0b, 0, &LDS[ATW2+BTW2]);
    stageA256k32(A, n0, 32, &LDS[TBW2]);
    stageB128k32(Bw, m0a, 32, &LDS[TBW2+ATW2]);
    stageB128k32(Bw, m0b, 32, &LDS[TBW2+ATW2+BTW2]);

    for (int T=0; T<NT; ++T){
        if (T == NT-1){ asm volatile("s_waitcnt vmcnt(0)" ::: "memory"); }
        else          { asm volatile("s_waitcnt vmcnt(4)" ::: "memory"); }
        __builtin_amdgcn_s_barrier();
        if (T+2 < NT){
            u16* buf = &LDS[((T+2)%3)*TBW2];
            int ktn = (T+2)*32;
            stageA256k32(A, n0, ktn, buf);
            stageB128k32(Bw, m0a, ktn, buf+ATW2);
            stageB128k32(Bw, m0b, ktn, buf+ATW2+BTW2);
        }
        const u16* Ab = &LDS[(T%3)*TBW2];
        const u16* B0 = Ab + ATW2;
        const u16* B1 = B0 + BTW2;
        bf16x8 af[4], b0[4], b1[4];
        #pragma unroll
        for (int f=0; f<4; ++f)
            af[f] = *(const bf16x8*)&Ab[(rb + f*16 + lrow)*32 + lcol];
        #pragma unroll
        for (int g=0; g<4; ++g){
            b0[g] = *(const bf16x8*)&B0[(cb + g*16 + lrow)*32 + lcol];
            b1[g] = *(const bf16x8*)&B1[(cb + g*16 + lrow)*32 + lcol];
        }
        __builtin_amdgcn_s_setprio(1);
        #pragma unroll
        for (int f=0; f<4; ++f)
            #pragma unroll
            for (int g=0; g<4; ++g){
                accA[f][g] = __builtin_amdgcn_mfma_f32_16x16x32_bf16(af[f], b0[g], accA[f][g], 0,0,0);
                accB[f][g] = __builtin_amdgcn_mfma_f32_16x16x32_bf16(af[f], b1[g], accB[f][g], 0,0,0);
            }
        __builtin_amdgcn_s_setprio(0);
    }

    // epilogue: two panels, sequential gt-tile scans
    u16* gt = (u16*)LDS;   // [256][128] u16 = 64KB (aliases staging, dead)
    int b = n0 >> 12;
    int tid = threadIdx.x;
    #pragma unroll
    for (int pan=0; pan<2; ++pan){
        int m0p = pan ? m0b : m0a;
        __syncthreads();   // prior reads of LDS (tiles or prev gt scan) done
        #pragma unroll
        for (int fm=0; fm<4; ++fm)
            #pragma unroll
            for (int g=0; g<4; ++g)
                #pragma unroll
                for (int q=0; q<4; ++q){
                    int rr = rb + fm*16 + er + q;
                    int cc = cb + g*16 + ec;
                    u16 hv = f2b(pan ? accB[fm][g][q] : accA[fm][g][q]);
                    outB[(size_t)(n0 + rr)*1024 + (m0p + cc)] = hv;
                    gt[rr*128 + cc] = hv;
                }
        __syncthreads();
        // scan: 512 threads, p = tid&63 (64 states), h = tid>>6 (8 chunks of 32)
        int p = tid & 63, h = tid >> 6;
        int P = (m0p >> 1) + p;
        int c = ((n0 & 4095) >> 5) + h;
        float Ar = prm[P], Ai = prm[Pz+P];
        float fre = prm[2*Pz+P], fim = prm[3*Pz+P];
        float xr = 0.f, xi = 0.f;
        int base = h*32*128 + 2*p;
        #pragma unroll 8
        for (int r = 0; r < 32; ++r){
            u32 v = *(const u32*)&gt[base + r*128];
            float gr = b2f((u16)(v & 0xffff));
            float gi = b2f((u16)(v >> 16));
            float br = fre*gr - fim*gi;
            float bi = fre*gi + fim*gr;
            float nr2 = Ar*xr - Ai*xi + br;
            float ni2 = Ar*xi + Ai*xr + bi;
            xr = nr2; xi = ni2;
        }
        size_t ci = ((size_t)(b*NC + c))*Pz + P;
        ERe[ci] = xr; EIm[ci] = xi;
    }
}

// ---------------- scan combine (NC=128 chunks; 32 blocks x 64 thr) ----------
__global__ __launch_bounds__(64) void scan_combine(const float* __restrict__ ERe,
                                                   const float* __restrict__ EIm,
                                                   const float* __restrict__ prm,
                                                   float* __restrict__ SinRe,
                                                   float* __restrict__ SinIm){
    int gt = blockIdx.x*64 + threadIdx.x;   // over B*P
    int b = gt / Pz, p = gt % Pz;
    float Ar = prm[4*Pz+p], Ai = prm[5*Pz+p];
    float Sr = 0.f, Si = 0.f;
    for (int c = 0; c < NC; ++c) {
        size_t idx = ((size_t)(b*NC + c))*Pz + p;
        SinRe[idx] = Sr; SinIm[idx] = Si;
        float er = ERe[idx], ei = EIm[idx];
        float nr = Ar*Sr - Ai*Si + er;
        float ni = Ar*Si + Ai*Sr + ei;
        Sr = nr; Si = ni;
    }
}

// ---------------- scan phase2: interleaved, short8 (16B) per row ------------
__global__ __launch_bounds__(64) void scan_phase2(u16* __restrict__ g,
                                                  const float* __restrict__ prm,
                                                  const float* __restrict__ SinRe,
                                                  const float* __restrict__ SinIm){
    int t = blockIdx.x;
    int ph = t & 1; t >>= 1;
    int c  = t % NC;
    int b  = t / NC;
    int p0 = ph*256 + threadIdx.x*4;         // first of 4 states
    int cbi = 2*p0;
    size_t base = ((size_t)(b*Lz + c*CL))*1024;
    size_t ci = ((size_t)(b*NC + c))*Pz + p0;
    float Ar[4], Ai[4], fr[4], fi[4], xr[4], xi[4];
    f32x4 sr4 = *(const f32x4*)&SinRe[ci];
    f32x4 si4 = *(const f32x4*)&SinIm[ci];
    #pragma unroll
    for (int j=0;j<4;++j){
        Ar[j]=prm[p0+j]; Ai[j]=prm[Pz+p0+j];
        fr[j]=prm[2*Pz+p0+j]; fi[j]=prm[3*Pz+p0+j];
        xr[j]=sr4[j]; xi[j]=si4[j];
    }
    for (int ll=0; ll<CL; ++ll){
        short8v v8 = *(const short8v*)&g[base + cbi];
        short8v o8;
        #pragma unroll
        for (int j=0;j<4;++j){
            float gr = b2f((u16)v8[2*j]), gi = b2f((u16)v8[2*j+1]);
            float br = fr[j]*gr - fi[j]*gi;
            float bi = fr[j]*gi + fi[j]*gr;
            float nr = Ar[j]*xr[j] - Ai[j]*xi[j] + br;
            float ni = Ar[j]*xi[j] + Ai[j]*xr[j] + bi;
            xr[j]=nr; xi[j]=ni;
            o8[2*j]   = (short)f2b(nr);
            o8[2*j+1] = (short)f2b(ni);
        }
        *(short8v*)&g[base + cbi] = o8;
        base += 1024;
    }
}

extern "C" void kernel_launch(void* const* d_in, const int* in_sizes, int n_in,
                              void* d_out, int out_size, void* d_ws, size_t ws_size,
                              hipStream_t stream) {
    const float* x        = (const float*)d_in[0];
    const float* ln1_w    = (const float*)d_in[1];
    const float* ln1_b    = (const float*)d_in[2];
    const float* Lre      = (const float*)d_in[3];
    const float* Lim      = (const float*)d_in[4];
    const float* B_re     = (const float*)d_in[5];
    const float* B_im     = (const float*)d_in[6];
    const float* C_re     = (const float*)d_in[7];
    const float* C_im     = (const float*)d_in[8];
    const float* Dv       = (const float*)d_in[9];
    const float* log_step = (const float*)d_in[10];
    const float* ln2_w    = (const float*)d_in[11];
    const float* ln2_b    = (const float*)d_in[12];
    const float* W_enc    = (const float*)d_in[13];
    const float* W_dec    = (const float*)d_in[14];
    float* out = (float*)d_out;

    const size_t NH = (size_t)Nz*Hz;   // 8388608
    char* W = (char*)d_ws;
    u16*   fxb  = (u16*)  (W);                    // [N,512] bf16: fx, later ff
    u16*   g    = (u16*)  (W + NH*2);             // [N,1024] bf16 interleaved: g -> xs
    u16*   hb   = (u16*)  (W + NH*6);             // [N,512] bf16: h
    u16*   fx2b = (u16*)  (W + NH*8);             // [N,512] bf16: fx2
    float* ERe  = (float*)(W + NH*10);
    float* EIm  = ERe + CS;
    float* SinRe= EIm + CS;
    float* SinIm= SinRe + CS;
    float* prm  = SinIm + CS;                     // 6*Pz f32
    u16*   Bcat = (u16*)(prm + 6*Pz);             // [1024,512] interleaved rows
    u16*   Ccat = Bcat + 1024*512;                // [512,1024] interleaved cols
    u16*   Wenc = Ccat + 512*1024;                // [1024,512]
    u16*   Wdec = Wenc + 1024*512;                // [512,512]

    // LN1 + weight converts + SSM setup, one co-scheduled launch
    prep_kernel<<<dim3(LN1B + 6*1024 + 2), dim3(256), 0, stream>>>(
        x, ln1_w, ln1_b, B_re, B_im, C_re, C_im, W_enc, W_dec,
        Lre, Lim, log_step, fxb, Bcat, Ccat, Wenc, Wdec, prm);

    // GEMM1 + fused scan-phase1, 2-m-panel: g + E    grid 256 = 1 round
    gemm1_scan2<<<dim3(256), dim3(512), 0, stream>>>(fxb, Bcat, g, prm, ERe, EIm);

    // scan combine + phase2 (in place over g)
    scan_combine<<<dim3((Bz*Pz)/64), dim3(64), 0, stream>>>(ERe, EIm, prm, SinRe, SinIm);
    scan_phase2<<<dim3(Bz*NC*2), dim3(64), 0, stream>>>(g, prm, SinRe, SinIm);

    // GEMM2 (Y): h = gelu(2*(xs@Ccat^T) + D*fx) + fx -> hb   grid 64x4 = 256
    gemmv<1024,EY><<<dim3(Nz/256, 512/128), dim3(512), 0, stream>>>(
        g, Ccat, 512, hb, fxb, Dv, nullptr, nullptr);

    // LN2: hb -> fx2b (bf16)
    ln_kernel<u16><<<dim3(Nz/4), dim3(256), 0, stream>>>(hb, ln2_w, ln2_b, fx2b);

    // GEMM3 + fused GEGLU, 2-n-panel persistent: ff -> fxb   grid 32x8 = 256
    gemmv<512,EGLU><<<dim3(Nz/512, 1024/128), dim3(512), 0, stream>>>(
        fx2b, Wenc, 1024, fxb, nullptr, nullptr, nullptr, nullptr);

    // GEMM4: out = ff @ Wdec^T + fx2   grid 64x4 = 256
    gemmv<512,ERES><<<dim3(Nz/256, 512/128), dim3(512), 0, stream>>>(
        fxb, Wdec, 512, nullptr, nullptr, nullptr, fx2b, out);
}